// Round 5
// baseline (260.698 us; speedup 1.0000x reference)
//
#include <hip/hip_runtime.h>
#include <hip/hip_bf16.h>
#include <cstdint>

#define N_NODES 4096
#define STRIDE  384      // max degree ~261 expected (Binom(4096,0.05) max-order stat)
#define SWPAD   (STRIDE + 8)   // 392 % 32 == 8 -> head rows land on distinct banks
#define QMAX    128      // per-quarter degree cap (mean 51, 11 sigma margin)

// bf16 helpers (manual, RNE encode / shift decode)
__device__ __forceinline__ unsigned short f2bf(float f) {
    unsigned u = __float_as_uint(f);
    unsigned r = u + 0x7fffu + ((u >> 16) & 1u);
    return (unsigned short)(r >> 16);
}
__device__ __forceinline__ float bf2f(unsigned short h) {
    return __uint_as_float((unsigned)h << 16);
}

// ---------------------------------------------------------------------------
// 1. Neighbor-list compaction: 256 thr/row, 4 waves scan quarters into LDS,
//    prefix-merge, coalesced u16 writeback. Serial ballot chain 16 -> 4.
// ---------------------------------------------------------------------------
__global__ __launch_bounds__(256) void build_nbr_kernel(
    const float* __restrict__ adj, unsigned short* __restrict__ nbr,
    int* __restrict__ cnt) {
    const int i    = blockIdx.x;
    const int tid  = threadIdx.x;
    const int wv   = tid >> 6;
    const int lane = tid & 63;
    __shared__ unsigned short s_buf[4][QMAX];
    __shared__ int s_cnt[4];
    const float4* row = (const float4*)(adj + (size_t)i * N_NODES);
    int base = 0;
#pragma unroll
    for (int it = 0; it < 4; it++) {    // wave scans 1024 cols = 256 f4
        float4 v = row[wv * 256 + it * 64 + lane];
        float e4[4] = {v.x, v.y, v.z, v.w};
        unsigned long long m4[4];
#pragma unroll
        for (int e = 0; e < 4; e++) m4[e] = __ballot(e4[e] != 0.0f);
#pragma unroll
        for (int e = 0; e < 4; e++) {
            int prefix = __popcll(m4[e] & ((1ull << lane) - 1ull));
            int pos = base + prefix;
            if (e4[e] != 0.0f && pos < QMAX)
                s_buf[wv][pos] = (unsigned short)(wv * 1024 + (it * 64 + lane) * 4 + e);
            base += __popcll(m4[e]);
        }
    }
    if (lane == 0) s_cnt[wv] = (base < QMAX) ? base : QMAX;
    __syncthreads();
    const int c0 = s_cnt[0], c1 = s_cnt[1], c2 = s_cnt[2], c3 = s_cnt[3];
    const int o1 = c0, o2 = c0 + c1, o3 = o2 + c2;
    int total = o3 + c3;
    if (total > STRIDE) total = STRIDE;
    for (int k = tid; k < total; k += 256) {
        int w, loc;
        if      (k < o1) { w = 0; loc = k; }
        else if (k < o2) { w = 1; loc = k - o1; }
        else if (k < o3) { w = 2; loc = k - o2; }
        else             { w = 3; loc = k - o3; }
        nbr[(size_t)i * STRIDE + k] = s_buf[w][loc];
    }
    if (tid == 0) cnt[i] = total;
}

// ---------------------------------------------------------------------------
// 2. Tiled fp32 GEMM (BK=32).
// ---------------------------------------------------------------------------
template<int BM, int BN, int BK, int TM, int TN>
__global__ __launch_bounds__(256) void sgemm_kernel(
    const float* __restrict__ A, const float* __restrict__ B,
    float* __restrict__ C, int M, int N, int K) {
    static_assert((BM / TM) * (BN / TN) == 256, "256 threads");
    __shared__ float As[BK][BM + 4];
    __shared__ float Bs[BK][BN + 4];
    const int tid  = threadIdx.x;
    const int tx   = tid % (BN / TN);
    const int ty   = tid / (BN / TN);
    const int row0 = blockIdx.y * BM;
    const int col0 = blockIdx.x * BN;
    float acc[TM][TN] = {};
    for (int k0 = 0; k0 < K; k0 += BK) {
        for (int i = tid; i < BM * BK / 4; i += 256) {
            int r  = i / (BK / 4);
            int kq = i % (BK / 4);
            float4 v = *(const float4*)(A + (size_t)(row0 + r) * K + k0 + kq * 4);
            As[kq * 4 + 0][r] = v.x;
            As[kq * 4 + 1][r] = v.y;
            As[kq * 4 + 2][r] = v.z;
            As[kq * 4 + 3][r] = v.w;
        }
        for (int i = tid; i < BK * BN / 4; i += 256) {
            int r  = i / (BN / 4);
            int cq = i % (BN / 4);
            *(float4*)&Bs[r][cq * 4] =
                *(const float4*)(B + (size_t)(k0 + r) * N + col0 + cq * 4);
        }
        __syncthreads();
#pragma unroll
        for (int kk = 0; kk < BK; kk++) {
            float a[TM], b[TN];
#pragma unroll
            for (int t = 0; t < TM; t++) a[t] = As[kk][ty * TM + t];
#pragma unroll
            for (int u = 0; u < TN; u++) b[u] = Bs[kk][tx * TN + u];
#pragma unroll
            for (int t = 0; t < TM; t++)
#pragma unroll
                for (int u = 0; u < TN; u++) acc[t][u] += a[t] * b[u];
        }
        __syncthreads();
    }
#pragma unroll
    for (int t = 0; t < TM; t++)
#pragma unroll
        for (int u4 = 0; u4 < TN / 4; u4++) {
            float4 v = make_float4(acc[t][u4 * 4 + 0], acc[t][u4 * 4 + 1],
                                   acc[t][u4 * 4 + 2], acc[t][u4 * 4 + 3]);
            *(float4*)(C + (size_t)(row0 + ty * TM + t) * N + col0 + tx * TN + u4 * 4) = v;
        }
}

// ---------------------------------------------------------------------------
// 3a. Layer-1 scores + bf16 shadow copy of h1 (one wave per node).
// ---------------------------------------------------------------------------
__global__ __launch_bounds__(64) void scores1_kernel(
    const float* __restrict__ h, const float* __restrict__ att_s,
    const float* __restrict__ att_d, float* __restrict__ as_,
    float* __restrict__ ad_, unsigned short* __restrict__ hg) {
    const int n = blockIdx.x, lane = threadIdx.x;
    const float4 a  = *(const float4*)(h + (size_t)n * 512 + lane * 8);
    const float4 b  = *(const float4*)(h + (size_t)n * 512 + lane * 8 + 4);
    const float4 sa = *(const float4*)(att_s + lane * 8);
    const float4 sb = *(const float4*)(att_s + lane * 8 + 4);
    const float4 da = *(const float4*)(att_d + lane * 8);
    const float4 db = *(const float4*)(att_d + lane * 8 + 4);
    float s = a.x*sa.x + a.y*sa.y + a.z*sa.z + a.w*sa.w
            + b.x*sb.x + b.y*sb.y + b.z*sb.z + b.w*sb.w;
    float d = a.x*da.x + a.y*da.y + a.z*da.z + a.w*da.w
            + b.x*db.x + b.y*db.y + b.z*db.z + b.w*db.w;
#pragma unroll
    for (int off = 1; off < 8; off <<= 1) {
        s += __shfl_xor(s, off);
        d += __shfl_xor(d, off);
    }
    if ((lane & 7) == 0) {
        as_[n * 8 + (lane >> 3)] = s;
        ad_[n * 8 + (lane >> 3)] = d;
    }
    uint4 p;
    p.x = (unsigned)f2bf(a.x) | ((unsigned)f2bf(a.y) << 16);
    p.y = (unsigned)f2bf(a.z) | ((unsigned)f2bf(a.w) << 16);
    p.z = (unsigned)f2bf(b.x) | ((unsigned)f2bf(b.y) << 16);
    p.w = (unsigned)f2bf(b.z) | ((unsigned)f2bf(b.w) << 16);
    *(uint4*)(hg + (size_t)n * 512 + lane * 8) = p;
}

// ---------------------------------------------------------------------------
// 3b. Layer-2 scores + bf16 shadow copy of h2 (one wave per node, C=128,H=1).
// ---------------------------------------------------------------------------
__global__ __launch_bounds__(64) void scores2_kernel(
    const float* __restrict__ h, const float* __restrict__ att_s,
    const float* __restrict__ att_d, float* __restrict__ as_,
    float* __restrict__ ad_, unsigned short* __restrict__ hg) {
    const int n = blockIdx.x, lane = threadIdx.x;
    float v0 = h[(size_t)n * 128 + lane];
    float v1 = h[(size_t)n * 128 + lane + 64];
    float s = v0 * att_s[lane] + v1 * att_s[lane + 64];
    float d = v0 * att_d[lane] + v1 * att_d[lane + 64];
#pragma unroll
    for (int off = 32; off; off >>= 1) {
        s += __shfl_xor(s, off);
        d += __shfl_xor(d, off);
    }
    if (lane == 0) { as_[n] = s; ad_[n] = d; }
    hg[(size_t)n * 128 + lane]      = f2bf(v0);
    hg[(size_t)n * 128 + lane + 64] = f2bf(v1);
}

// ---------------------------------------------------------------------------
// 4. Layer-1 sparse aggregate: ONE WAVE per (row, head-half). 4 heads x 16
//    lanes, no barriers, LDS 7 KB (23 blocks/CU). Pass 3: unroll x8, s_nbr
//    read as uint4 (8 ids/inst), s_w as float4.
// ---------------------------------------------------------------------------
__global__ __launch_bounds__(64) void attn1_kernel(
    const unsigned short* __restrict__ h1g, const float* __restrict__ asrc,
    const float* __restrict__ adst, const unsigned short* __restrict__ nbr,
    const int* __restrict__ cnt, const float* __restrict__ b1,
    float* __restrict__ out1) {
    const int i    = blockIdx.x >> 1;      // row
    const int hlf  = blockIdx.x & 1;       // head half: 0 -> heads 0-3, 1 -> 4-7
    const int lane = threadIdx.x;
    const int hs   = lane >> 4;            // head-in-half 0..3
    const int l16  = lane & 15;
    const int head = hlf * 4 + hs;
    __shared__ __align__(16) unsigned short s_nbr[STRIDE];
    __shared__ __align__(16) float s_w[4][SWPAD];
    const int n = cnt[i];
    for (int j = lane; j < n; j += 64) s_nbr[j] = nbr[(size_t)i * STRIDE + j];
    // same-wave LDS write->read: ordered by lgkmcnt, no barrier needed

    // pass 1: scores, per-head 4B gathers (16 edges x 4 heads per wave-inst)
    const float ad = adst[i * 8 + head];
    float m = -1e30f;
    for (int j = l16; j < n; j += 16) {
        float s = asrc[(int)s_nbr[j] * 8 + head] + ad;
        s = (s > 0.f) ? s : 0.2f * s;
        s_w[hs][j] = s;
        m = fmaxf(m, s);
    }
#pragma unroll
    for (int off = 8; off; off >>= 1) m = fmaxf(m, __shfl_xor(m, off));
    float l = 0.f;
    for (int j = l16; j < n; j += 16) {
        float e = __expf(s_w[hs][j] - m);
        s_w[hs][j] = e;
        l += e;
    }
#pragma unroll
    for (int off = 8; off; off >>= 1) l += __shfl_xor(l, off);
    const float inv = 1.0f / l;

    // pass 3: bf16 weighted gather, unroll x8 (8 loads in flight / thread)
    const int c0 = head * 64 + l16 * 4;
    const unsigned short* __restrict__ hb = h1g + c0;
    float4 a0 = {0,0,0,0}, a1 = {0,0,0,0}, a2 = {0,0,0,0}, a3 = {0,0,0,0};
    int j = 0;
    for (; j + 8 <= n; j += 8) {
        uint4 idp = *(const uint4*)&s_nbr[j];          // 8 u16 ids
        float4 w03 = *(const float4*)&s_w[hs][j];
        float4 w47 = *(const float4*)&s_w[hs][j + 4];
        int i0 = idp.x & 0xffff, i1 = idp.x >> 16;
        int i2 = idp.y & 0xffff, i3 = idp.y >> 16;
        int i4 = idp.z & 0xffff, i5 = idp.z >> 16;
        int i6 = idp.w & 0xffff, i7 = idp.w >> 16;
        ushort4 v0 = *(const ushort4*)(hb + (size_t)i0 * 512);
        ushort4 v1 = *(const ushort4*)(hb + (size_t)i1 * 512);
        ushort4 v2 = *(const ushort4*)(hb + (size_t)i2 * 512);
        ushort4 v3 = *(const ushort4*)(hb + (size_t)i3 * 512);
        ushort4 v4 = *(const ushort4*)(hb + (size_t)i4 * 512);
        ushort4 v5 = *(const ushort4*)(hb + (size_t)i5 * 512);
        ushort4 v6 = *(const ushort4*)(hb + (size_t)i6 * 512);
        ushort4 v7 = *(const ushort4*)(hb + (size_t)i7 * 512);
        a0.x += w03.x*bf2f(v0.x); a0.y += w03.x*bf2f(v0.y); a0.z += w03.x*bf2f(v0.z); a0.w += w03.x*bf2f(v0.w);
        a1.x += w03.y*bf2f(v1.x); a1.y += w03.y*bf2f(v1.y); a1.z += w03.y*bf2f(v1.z); a1.w += w03.y*bf2f(v1.w);
        a2.x += w03.z*bf2f(v2.x); a2.y += w03.z*bf2f(v2.y); a2.z += w03.z*bf2f(v2.z); a2.w += w03.z*bf2f(v2.w);
        a3.x += w03.w*bf2f(v3.x); a3.y += w03.w*bf2f(v3.y); a3.z += w03.w*bf2f(v3.z); a3.w += w03.w*bf2f(v3.w);
        a0.x += w47.x*bf2f(v4.x); a0.y += w47.x*bf2f(v4.y); a0.z += w47.x*bf2f(v4.z); a0.w += w47.x*bf2f(v4.w);
        a1.x += w47.y*bf2f(v5.x); a1.y += w47.y*bf2f(v5.y); a1.z += w47.y*bf2f(v5.z); a1.w += w47.y*bf2f(v5.w);
        a2.x += w47.z*bf2f(v6.x); a2.y += w47.z*bf2f(v6.y); a2.z += w47.z*bf2f(v6.z); a2.w += w47.z*bf2f(v6.w);
        a3.x += w47.w*bf2f(v7.x); a3.y += w47.w*bf2f(v7.y); a3.z += w47.w*bf2f(v7.z); a3.w += w47.w*bf2f(v7.w);
    }
    for (; j < n; j++) {
        float w = s_w[hs][j];
        ushort4 v = *(const ushort4*)(hb + (size_t)s_nbr[j] * 512);
        a0.x += w*bf2f(v.x); a0.y += w*bf2f(v.y); a0.z += w*bf2f(v.z); a0.w += w*bf2f(v.w);
    }
    float4 acc = make_float4(a0.x + a1.x + a2.x + a3.x,
                             a0.y + a1.y + a2.y + a3.y,
                             a0.z + a1.z + a2.z + a3.z,
                             a0.w + a1.w + a2.w + a3.w);
    float4 bb = *(const float4*)(b1 + c0);
    float o0 = acc.x * inv + bb.x, o1 = acc.y * inv + bb.y;
    float o2 = acc.z * inv + bb.z, o3 = acc.w * inv + bb.w;
    o0 = (o0 > 0.f) ? o0 : 0.01f * o0;
    o1 = (o1 > 0.f) ? o1 : 0.01f * o1;
    o2 = (o2 > 0.f) ? o2 : 0.01f * o2;
    o3 = (o3 > 0.f) ? o3 : 0.01f * o3;
    *(float4*)(out1 + (size_t)i * 512 + c0) = make_float4(o0, o1, o2, o3);
}

// ---------------------------------------------------------------------------
// 5. Layer-2 sparse aggregate: ONE WAVE per row, 2 ch/thread via packed
//    bf16-pair uint loads, no barriers, unroll x8.
// ---------------------------------------------------------------------------
__global__ __launch_bounds__(64) void attn2_kernel(
    const unsigned short* __restrict__ h2g, const float* __restrict__ asrc,
    const float* __restrict__ adst, const unsigned short* __restrict__ nbr,
    const int* __restrict__ cnt, const float* __restrict__ b2,
    float* __restrict__ out) {
    const int i    = blockIdx.x;
    const int lane = threadIdx.x;
    __shared__ __align__(16) unsigned short s_nbr[STRIDE];
    __shared__ __align__(16) float s_w[STRIDE];
    const int n = cnt[i];
    for (int j = lane; j < n; j += 64) s_nbr[j] = nbr[(size_t)i * STRIDE + j];

    const float ad = adst[i];
    float m = -1e30f;
    for (int j = lane; j < n; j += 64) {
        float s = asrc[(int)s_nbr[j]] + ad;
        s = (s > 0.f) ? s : 0.2f * s;
        s_w[j] = s;
        m = fmaxf(m, s);
    }
#pragma unroll
    for (int off = 32; off; off >>= 1) m = fmaxf(m, __shfl_xor(m, off));
    float l = 0.f;
    for (int j = lane; j < n; j += 64) {
        float e = __expf(s_w[j] - m);
        s_w[j] = e;
        l += e;
    }
#pragma unroll
    for (int off = 32; off; off >>= 1) l += __shfl_xor(l, off);
    const float inv = 1.0f / l;

    // gather: thread owns channels {2*lane, 2*lane+1} -> one uint (bf16 pair)
    const unsigned* __restrict__ hb = (const unsigned*)h2g;   // row stride 64 uints
    float e0 = 0.f, e1 = 0.f, f0 = 0.f, f1 = 0.f;
    float g0 = 0.f, g1 = 0.f, k0 = 0.f, k1 = 0.f;
    int j = 0;
    for (; j + 8 <= n; j += 8) {
        uint4 idp = *(const uint4*)&s_nbr[j];
        float4 w03 = *(const float4*)&s_w[j];
        float4 w47 = *(const float4*)&s_w[j + 4];
        int i0 = idp.x & 0xffff, i1 = idp.x >> 16;
        int i2 = idp.y & 0xffff, i3 = idp.y >> 16;
        int i4 = idp.z & 0xffff, i5 = idp.z >> 16;
        int i6 = idp.w & 0xffff, i7 = idp.w >> 16;
        unsigned u0 = hb[(size_t)i0 * 64 + lane];
        unsigned u1 = hb[(size_t)i1 * 64 + lane];
        unsigned u2 = hb[(size_t)i2 * 64 + lane];
        unsigned u3 = hb[(size_t)i3 * 64 + lane];
        unsigned u4 = hb[(size_t)i4 * 64 + lane];
        unsigned u5 = hb[(size_t)i5 * 64 + lane];
        unsigned u6 = hb[(size_t)i6 * 64 + lane];
        unsigned u7 = hb[(size_t)i7 * 64 + lane];
        e0 += w03.x * __uint_as_float(u0 << 16); e1 += w03.x * __uint_as_float(u0 & 0xffff0000u);
        f0 += w03.y * __uint_as_float(u1 << 16); f1 += w03.y * __uint_as_float(u1 & 0xffff0000u);
        g0 += w03.z * __uint_as_float(u2 << 16); g1 += w03.z * __uint_as_float(u2 & 0xffff0000u);
        k0 += w03.w * __uint_as_float(u3 << 16); k1 += w03.w * __uint_as_float(u3 & 0xffff0000u);
        e0 += w47.x * __uint_as_float(u4 << 16); e1 += w47.x * __uint_as_float(u4 & 0xffff0000u);
        f0 += w47.y * __uint_as_float(u5 << 16); f1 += w47.y * __uint_as_float(u5 & 0xffff0000u);
        g0 += w47.z * __uint_as_float(u6 << 16); g1 += w47.z * __uint_as_float(u6 & 0xffff0000u);
        k0 += w47.w * __uint_as_float(u7 << 16); k1 += w47.w * __uint_as_float(u7 & 0xffff0000u);
    }
    for (; j < n; j++) {
        float w = s_w[j];
        unsigned u = hb[(size_t)s_nbr[j] * 64 + lane];
        e0 += w * __uint_as_float(u << 16);
        e1 += w * __uint_as_float(u & 0xffff0000u);
    }
    float2 bb = *(const float2*)(b2 + lane * 2);
    float o0 = (e0 + f0 + g0 + k0) * inv + bb.x;
    float o1 = (e1 + f1 + g1 + k1) * inv + bb.y;
    o0 = (o0 > 0.f) ? o0 : 0.01f * o0;
    o1 = (o1 > 0.f) ? o1 : 0.01f * o1;
    *(float2*)(out + (size_t)i * 128 + lane * 2) = make_float2(o0, o1);
}

// ---------------------------------------------------------------------------
extern "C" void kernel_launch(void* const* d_in, const int* in_sizes, int n_in,
                              void* d_out, int out_size, void* d_ws, size_t ws_size,
                              hipStream_t stream) {
    const float* x        = (const float*)d_in[0];   // [4096,256]
    const float* adj      = (const float*)d_in[1];   // [4096,4096]
    const float* w1       = (const float*)d_in[2];   // [256,512]
    const float* att_src1 = (const float*)d_in[3];   // [8,64]
    const float* att_dst1 = (const float*)d_in[4];
    const float* b1       = (const float*)d_in[5];   // [512]
    const float* w2       = (const float*)d_in[6];   // [512,128]
    const float* att_src2 = (const float*)d_in[7];   // [1,128]
    const float* att_dst2 = (const float*)d_in[8];
    const float* b2       = (const float*)d_in[9];   // [128]
    float* out = (float*)d_out;                      // [4096,128]

    float* ws   = (float*)d_ws;
    float* h1   = ws;                               // 4096*512 f
    float* out1 = h1 + 4096 * 512;                  // 4096*512 f
    float* h2   = out1 + 4096 * 512;                // 4096*128 f
    float* as1  = h2 + 4096 * 128;                  // 4096*8 f
    float* ad1  = as1 + 4096 * 8;                   // 4096*8 f
    float* as2  = ad1 + 4096 * 8;                   // 4096 f
    float* ad2  = as2 + 4096;                       // 4096 f
    int*   cnt  = (int*)(ad2 + 4096);               // 4096 i32
    unsigned short* nbr = (unsigned short*)(cnt + 4096);   // 4096*STRIDE u16
    unsigned short* h1g = nbr + (size_t)4096 * STRIDE;     // 4096*512 u16 (4 MB)
    unsigned short* h2g = h1g + (size_t)4096 * 512;        // 4096*128 u16 (1 MB)

    build_nbr_kernel<<<N_NODES, 256, 0, stream>>>(adj, nbr, cnt);

    // layer 1: h1 = x @ w1   (4096x256 @ 256x512)
    sgemm_kernel<64, 64, 32, 4, 4><<<dim3(512 / 64, 4096 / 64), 256, 0, stream>>>(
        x, w1, h1, 4096, 512, 256);
    scores1_kernel<<<N_NODES, 64, 0, stream>>>(h1, att_src1, att_dst1, as1, ad1, h1g);
    attn1_kernel<<<N_NODES * 2, 64, 0, stream>>>(h1g, as1, ad1, nbr, cnt, b1, out1);

    // layer 2: h2 = out1 @ w2  (4096x512 @ 512x128)
    sgemm_kernel<32, 64, 32, 2, 4><<<dim3(128 / 64, 4096 / 32), 256, 0, stream>>>(
        out1, w2, h2, 4096, 128, 512);
    scores2_kernel<<<N_NODES, 64, 0, stream>>>(h2, att_src2, att_dst2, as2, ad2, h2g);
    attn2_kernel<<<N_NODES, 64, 0, stream>>>(h2g, as2, ad2, nbr, cnt, b2, out);
}

// Round 6
// 251.506 us; speedup vs baseline: 1.0365x; 1.0365x over previous
//
#include <hip/hip_runtime.h>
#include <hip/hip_bf16.h>
#include <cstdint>

#define N_NODES 4096
#define STRIDE  384      // max degree ~261 expected (Binom(4096,0.05) max-order stat)
#define QMAX    128      // per-quarter degree cap in build_nbr
#define WPDIM   (STRIDE / 2 + 8)   // packed weight-pairs per head row (uints)

typedef _Float16 half2v __attribute__((ext_vector_type(2)));

// ---- fp16 pack/dot helpers ------------------------------------------------
__device__ __forceinline__ unsigned pkrtz(float a, float b) {   // (a=lo, b=hi)
    return __builtin_bit_cast(unsigned, __builtin_amdgcn_cvt_pkrtz(a, b));
}
// pair of EVEN halves: result = (a.lo16, b.lo16)  [a in low]
__device__ __forceinline__ unsigned pk_lo(unsigned a, unsigned b) {
#if __has_builtin(__builtin_amdgcn_perm)
    return __builtin_amdgcn_perm(b, a, 0x05040100u);
#else
    return (a & 0xffffu) | (b << 16);
#endif
}
// pair of ODD halves: result = (a.hi16, b.hi16)
__device__ __forceinline__ unsigned pk_hi(unsigned a, unsigned b) {
#if __has_builtin(__builtin_amdgcn_perm)
    return __builtin_amdgcn_perm(b, a, 0x07060302u);
#else
    return (a >> 16) | (b & 0xffff0000u);
#endif
}
__device__ __forceinline__ float fdot2f(unsigned v, unsigned w, float acc) {
#if __has_builtin(__builtin_amdgcn_fdot2)
    return __builtin_amdgcn_fdot2(__builtin_bit_cast(half2v, v),
                                  __builtin_bit_cast(half2v, w), acc, false);
#else
    half2v a = __builtin_bit_cast(half2v, v), b = __builtin_bit_cast(half2v, w);
    return acc + (float)a.x * (float)b.x + (float)a.y * (float)b.y;
#endif
}
__device__ __forceinline__ float lrelu02(float s) { return (s > 0.f) ? s : 0.2f * s; }

// ---------------------------------------------------------------------------
// 1. Neighbor-list compaction (4 waves/row) + zero-init of score accumulators
//    (as1/ad1/as2/ad2 are atomicAdd targets in the fused GEMM epilogues).
// ---------------------------------------------------------------------------
__global__ __launch_bounds__(256) void build_nbr_kernel(
    const float* __restrict__ adj, unsigned short* __restrict__ nbr,
    int* __restrict__ cnt, float* __restrict__ as1, float* __restrict__ ad1,
    float* __restrict__ as2, float* __restrict__ ad2) {
    const int i    = blockIdx.x;
    const int tid  = threadIdx.x;
    const int wv   = tid >> 6;
    const int lane = tid & 63;
    if (tid < 8)  { as1[i * 8 + tid] = 0.f; ad1[i * 8 + tid] = 0.f; }
    if (tid == 8) { as2[i] = 0.f; }
    if (tid == 9) { ad2[i] = 0.f; }
    __shared__ unsigned short s_buf[4][QMAX];
    __shared__ int s_cnt[4];
    const float4* row = (const float4*)(adj + (size_t)i * N_NODES);
    int base = 0;
#pragma unroll
    for (int it = 0; it < 4; it++) {
        float4 v = row[wv * 256 + it * 64 + lane];
        float e4[4] = {v.x, v.y, v.z, v.w};
        unsigned long long m4[4];
#pragma unroll
        for (int e = 0; e < 4; e++) m4[e] = __ballot(e4[e] != 0.0f);
#pragma unroll
        for (int e = 0; e < 4; e++) {
            int prefix = __popcll(m4[e] & ((1ull << lane) - 1ull));
            int pos = base + prefix;
            if (e4[e] != 0.0f && pos < QMAX)
                s_buf[wv][pos] = (unsigned short)(wv * 1024 + (it * 64 + lane) * 4 + e);
            base += __popcll(m4[e]);
        }
    }
    if (lane == 0) s_cnt[wv] = (base < QMAX) ? base : QMAX;
    __syncthreads();
    const int c0 = s_cnt[0], c1 = s_cnt[1], c2 = s_cnt[2], c3 = s_cnt[3];
    const int o1 = c0, o2 = c0 + c1, o3 = o2 + c2;
    int total = o3 + c3;
    if (total > STRIDE) total = STRIDE;
    for (int k = tid; k < total; k += 256) {
        int w, loc;
        if      (k < o1) { w = 0; loc = k; }
        else if (k < o2) { w = 1; loc = k - o1; }
        else if (k < o3) { w = 2; loc = k - o2; }
        else             { w = 3; loc = k - o3; }
        nbr[(size_t)i * STRIDE + k] = s_buf[w][loc];
    }
    if (tid == 0) cnt[i] = total;
}

// ---------------------------------------------------------------------------
// 2. Tiled fp32 GEMM with fused epilogue: writes C in fp16 (shadow for the
//    gather kernels) and atomically accumulates per-row attention score
//    partials  as[row,h] += sum_c h[row,c]*att_s[c]  (same for ad).
//    H=8: head = col0/64 (BN=64 == one head). H=1: single head.
// ---------------------------------------------------------------------------
template<int BM, int BN, int BK, int TM, int TN, int H>
__global__ __launch_bounds__(256) void sgemm_att_kernel(
    const float* __restrict__ A, const float* __restrict__ B,
    unsigned short* __restrict__ C16,
    const float* __restrict__ att_s, const float* __restrict__ att_d,
    float* __restrict__ as_, float* __restrict__ ad_,
    int M, int N, int K) {
    static_assert((BM / TM) * (BN / TN) == 256, "256 threads");
    static_assert(TN == 4, "epilogue assumes TN=4");
    __shared__ float As[BK][BM + 4];
    __shared__ float Bs[BK][BN + 4];
    const int tid  = threadIdx.x;
    const int tx   = tid % (BN / TN);
    const int ty   = tid / (BN / TN);
    const int row0 = blockIdx.y * BM;
    const int col0 = blockIdx.x * BN;
    float acc[TM][TN] = {};
    for (int k0 = 0; k0 < K; k0 += BK) {
        for (int i = tid; i < BM * BK / 4; i += 256) {
            int r  = i / (BK / 4);
            int kq = i % (BK / 4);
            float4 v = *(const float4*)(A + (size_t)(row0 + r) * K + k0 + kq * 4);
            As[kq * 4 + 0][r] = v.x;
            As[kq * 4 + 1][r] = v.y;
            As[kq * 4 + 2][r] = v.z;
            As[kq * 4 + 3][r] = v.w;
        }
        for (int i = tid; i < BK * BN / 4; i += 256) {
            int r  = i / (BN / 4);
            int cq = i % (BN / 4);
            *(float4*)&Bs[r][cq * 4] =
                *(const float4*)(B + (size_t)(k0 + r) * N + col0 + cq * 4);
        }
        __syncthreads();
#pragma unroll
        for (int kk = 0; kk < BK; kk++) {
            float a[TM], b[TN];
#pragma unroll
            for (int t = 0; t < TM; t++) a[t] = As[kk][ty * TM + t];
#pragma unroll
            for (int u = 0; u < TN; u++) b[u] = Bs[kk][tx * TN + u];
#pragma unroll
            for (int t = 0; t < TM; t++)
#pragma unroll
                for (int u = 0; u < TN; u++) acc[t][u] += a[t] * b[u];
        }
        __syncthreads();
    }
    // epilogue: fp16 store + fused attention-score partials
    float asv[TN], adv[TN];
#pragma unroll
    for (int u = 0; u < TN; u++) {
        asv[u] = att_s[col0 + tx * TN + u];
        adv[u] = att_d[col0 + tx * TN + u];
    }
    const int head = (H > 1) ? (col0 >> 6) : 0;
#pragma unroll
    for (int t = 0; t < TM; t++) {
        const int row = row0 + ty * TM + t;
        uint2 pk;
        pk.x = pkrtz(acc[t][0], acc[t][1]);
        pk.y = pkrtz(acc[t][2], acc[t][3]);
        *(uint2*)(C16 + (size_t)row * N + col0 + tx * TN) = pk;
        float ps = 0.f, pd = 0.f;
#pragma unroll
        for (int u = 0; u < TN; u++) { ps += acc[t][u] * asv[u]; pd += acc[t][u] * adv[u]; }
#pragma unroll
        for (int off = 8; off; off >>= 1) {
            ps += __shfl_xor(ps, off);
            pd += __shfl_xor(pd, off);
        }
        if (tx == 0) {
            atomicAdd(&as_[row * H + head], ps);
            atomicAdd(&ad_[row * H + head], pd);
        }
    }
}

// ---------------------------------------------------------------------------
// 3. Layer-1 sparse aggregate. 128 thr = 2 independent waves (head halves),
//    no barriers. fp16 gathers + v_dot2_f32_f16 (edge pairs): per pair per
//    channel 1 v_perm + 1 fdot2. Packed fp16 weight pairs in LDS.
// ---------------------------------------------------------------------------
__global__ __launch_bounds__(128, 8) void attn1_kernel(
    const unsigned short* __restrict__ h1g, const float* __restrict__ asrc,
    const float* __restrict__ adst, const unsigned short* __restrict__ nbr,
    const int* __restrict__ cnt, const float* __restrict__ b1,
    float* __restrict__ out1) {
    const int i    = blockIdx.x;
    const int wv   = threadIdx.x >> 6;     // head half
    const int lane = threadIdx.x & 63;
    const int hs   = lane >> 4;            // head-in-half
    const int l16  = lane & 15;
    const int head = wv * 4 + hs;
    __shared__ __align__(16) unsigned short s_nbr[STRIDE + 16];
    __shared__ __align__(16) unsigned s_wp[2][4][WPDIM];
    const int n       = cnt[i];
    const int npairs  = (n + 1) >> 1;
    const int niter8  = (n + 7) >> 3;
    const int npadp   = niter8 * 4;
    // each wave fills the full list (duplicate identical writes are benign)
    for (int j = lane; j < n; j += 64) s_nbr[j] = nbr[(size_t)i * STRIDE + j];
    if (lane < npadp * 2 - n) s_nbr[n + lane] = 0;

    // pass 1: per-head max (stride-16 over edges)
    const float ad = adst[i * 8 + head];
    float m = -1e30f;
    for (int j = l16; j < n; j += 16)
        m = fmaxf(m, lrelu02(asrc[(int)s_nbr[j] * 8 + head] + ad));
#pragma unroll
    for (int off = 8; off; off >>= 1) m = fmaxf(m, __shfl_xor(m, off));

    // pass 2: recompute scores per edge pair, exp, pack fp16, store to LDS.
    // Denominator accumulated from the ROUNDED fp16 weights (bias cancels).
    float l = 0.f;
    for (int jp = l16; jp < npairs; jp += 16) {
        const int j0 = jp * 2, j1 = j0 + 1;
        float e0 = __expf(lrelu02(asrc[(int)s_nbr[j0] * 8 + head] + ad) - m);
        float e1 = 0.f;
        if (j1 < n)
            e1 = __expf(lrelu02(asrc[(int)s_nbr[j1] * 8 + head] + ad) - m);
        unsigned wp = pkrtz(e0, e1);
        half2v hw = __builtin_bit_cast(half2v, wp);
        l += (float)hw.x + (float)hw.y;
        s_wp[wv][hs][jp] = wp;
    }
#pragma unroll
    for (int off = 8; off; off >>= 1) l += __shfl_xor(l, off);
    const float inv = 1.0f / l;
    if (l16 < npadp - npairs) s_wp[wv][hs][npairs + l16] = 0u;   // zero pad pairs

    // pass 3: fp16 weighted gather, 4 edge-pairs (8 edges) per iteration
    const int c0 = head * 64 + l16 * 4;
    const unsigned short* __restrict__ hb = h1g + c0;
    float aA0 = 0.f, aA1 = 0.f, aA2 = 0.f, aA3 = 0.f;
    float aB0 = 0.f, aB1 = 0.f, aB2 = 0.f, aB3 = 0.f;
    for (int it = 0; it < niter8; ++it) {
        const uint4 idp = *(const uint4*)&s_nbr[it * 8];
        const uint4 wp4 = *(const uint4*)&s_wp[wv][hs][it * 4];
        const unsigned idv[4] = {idp.x, idp.y, idp.z, idp.w};
        const unsigned wpv[4] = {wp4.x, wp4.y, wp4.z, wp4.w};
#pragma unroll
        for (int p = 0; p < 4; p++) {
            const int iA = idv[p] & 0xffff, iB = idv[p] >> 16;
            const uint2 uA = *(const uint2*)(hb + (size_t)iA * 512);
            const uint2 uB = *(const uint2*)(hb + (size_t)iB * 512);
            if (p & 1) {
                aB0 = fdot2f(pk_lo(uA.x, uB.x), wpv[p], aB0);
                aB1 = fdot2f(pk_hi(uA.x, uB.x), wpv[p], aB1);
                aB2 = fdot2f(pk_lo(uA.y, uB.y), wpv[p], aB2);
                aB3 = fdot2f(pk_hi(uA.y, uB.y), wpv[p], aB3);
            } else {
                aA0 = fdot2f(pk_lo(uA.x, uB.x), wpv[p], aA0);
                aA1 = fdot2f(pk_hi(uA.x, uB.x), wpv[p], aA1);
                aA2 = fdot2f(pk_lo(uA.y, uB.y), wpv[p], aA2);
                aA3 = fdot2f(pk_hi(uA.y, uB.y), wpv[p], aA3);
            }
        }
    }
    const float4 bb = *(const float4*)(b1 + c0);
    float o0 = (aA0 + aB0) * inv + bb.x;
    float o1 = (aA1 + aB1) * inv + bb.y;
    float o2 = (aA2 + aB2) * inv + bb.z;
    float o3 = (aA3 + aB3) * inv + bb.w;
    o0 = (o0 > 0.f) ? o0 : 0.01f * o0;
    o1 = (o1 > 0.f) ? o1 : 0.01f * o1;
    o2 = (o2 > 0.f) ? o2 : 0.01f * o2;
    o3 = (o3 > 0.f) ? o3 : 0.01f * o3;
    *(float4*)(out1 + (size_t)i * 512 + c0) = make_float4(o0, o1, o2, o3);
}

// ---------------------------------------------------------------------------
// 4. Layer-2 sparse aggregate (1 head, 128 ch). 128 thr = 2 waves, each an
//    independent ROW. fp16 pair gathers + fdot2. Lane owns ch {2l, 2l+1}.
// ---------------------------------------------------------------------------
__global__ __launch_bounds__(128, 8) void attn2_kernel(
    const unsigned short* __restrict__ h2g, const float* __restrict__ asrc,
    const float* __restrict__ adst, const unsigned short* __restrict__ nbr,
    const int* __restrict__ cnt, const float* __restrict__ b2,
    float* __restrict__ out) {
    const int rw   = threadIdx.x >> 6;
    const int i    = blockIdx.x * 2 + rw;
    const int lane = threadIdx.x & 63;
    __shared__ __align__(16) unsigned short s_nbr[2][STRIDE + 16];
    __shared__ __align__(16) unsigned s_wp[2][WPDIM];
    const int n      = cnt[i];
    const int npairs = (n + 1) >> 1;
    const int niter8 = (n + 7) >> 3;
    const int npadp  = niter8 * 4;
    for (int j = lane; j < n; j += 64) s_nbr[rw][j] = nbr[(size_t)i * STRIDE + j];
    if (lane < npadp * 2 - n) s_nbr[rw][n + lane] = 0;

    const float ad = adst[i];
    float m = -1e30f;
    for (int j = lane; j < n; j += 64)
        m = fmaxf(m, lrelu02(asrc[(int)s_nbr[rw][j]] + ad));
#pragma unroll
    for (int off = 32; off; off >>= 1) m = fmaxf(m, __shfl_xor(m, off));

    float l = 0.f;
    for (int jp = lane; jp < npairs; jp += 64) {
        const int j0 = jp * 2, j1 = j0 + 1;
        float e0 = __expf(lrelu02(asrc[(int)s_nbr[rw][j0]] + ad) - m);
        float e1 = 0.f;
        if (j1 < n) e1 = __expf(lrelu02(asrc[(int)s_nbr[rw][j1]] + ad) - m);
        unsigned wp = pkrtz(e0, e1);
        half2v hw = __builtin_bit_cast(half2v, wp);
        l += (float)hw.x + (float)hw.y;
        s_wp[rw][jp] = wp;
    }
#pragma unroll
    for (int off = 32; off; off >>= 1) l += __shfl_xor(l, off);
    const float inv = 1.0f / l;
    if (lane < npadp - npairs) s_wp[rw][npairs + lane] = 0u;

    const unsigned* __restrict__ hb = (const unsigned*)h2g + lane;  // row stride 64
    float aE0 = 0.f, aO0 = 0.f, aE1 = 0.f, aO1 = 0.f;
    for (int it = 0; it < niter8; ++it) {
        const uint4 idp = *(const uint4*)&s_nbr[rw][it * 8];
        const uint4 wp4 = *(const uint4*)&s_wp[rw][it * 4];
        const unsigned idv[4] = {idp.x, idp.y, idp.z, idp.w};
        const unsigned wpv[4] = {wp4.x, wp4.y, wp4.z, wp4.w};
#pragma unroll
        for (int p = 0; p < 4; p++) {
            const int iA = idv[p] & 0xffff, iB = idv[p] >> 16;
            const unsigned uA = hb[(size_t)iA * 64];
            const unsigned uB = hb[(size_t)iB * 64];
            if (p & 1) {
                aE1 = fdot2f(pk_lo(uA, uB), wpv[p], aE1);
                aO1 = fdot2f(pk_hi(uA, uB), wpv[p], aO1);
            } else {
                aE0 = fdot2f(pk_lo(uA, uB), wpv[p], aE0);
                aO0 = fdot2f(pk_hi(uA, uB), wpv[p], aO0);
            }
        }
    }
    const float2 bb = *(const float2*)(b2 + lane * 2);
    float o0 = (aE0 + aE1) * inv + bb.x;
    float o1 = (aO0 + aO1) * inv + bb.y;
    o0 = (o0 > 0.f) ? o0 : 0.01f * o0;
    o1 = (o1 > 0.f) ? o1 : 0.01f * o1;
    *(float2*)(out + (size_t)i * 128 + lane * 2) = make_float2(o0, o1);
}

// ---------------------------------------------------------------------------
extern "C" void kernel_launch(void* const* d_in, const int* in_sizes, int n_in,
                              void* d_out, int out_size, void* d_ws, size_t ws_size,
                              hipStream_t stream) {
    const float* x        = (const float*)d_in[0];   // [4096,256]
    const float* adj      = (const float*)d_in[1];   // [4096,4096]
    const float* w1       = (const float*)d_in[2];   // [256,512]
    const float* att_src1 = (const float*)d_in[3];   // [8,64]
    const float* att_dst1 = (const float*)d_in[4];
    const float* b1       = (const float*)d_in[5];   // [512]
    const float* w2       = (const float*)d_in[6];   // [512,128]
    const float* att_src2 = (const float*)d_in[7];   // [1,128]
    const float* att_dst2 = (const float*)d_in[8];
    const float* b2       = (const float*)d_in[9];   // [128]
    float* out = (float*)d_out;                      // [4096,128]

    float* ws   = (float*)d_ws;
    float* out1 = ws;                               // 4096*512 f
    float* as1  = out1 + 4096 * 512;                // 4096*8 f
    float* ad1  = as1 + 4096 * 8;                   // 4096*8 f
    float* as2  = ad1 + 4096 * 8;                   // 4096 f
    float* ad2  = as2 + 4096;                       // 4096 f
    int*   cnt  = (int*)(ad2 + 4096);               // 4096 i32
    unsigned short* nbr = (unsigned short*)(cnt + 4096);   // 4096*STRIDE u16
    unsigned short* h1g = nbr + (size_t)4096 * STRIDE;     // 4096*512 fp16
    unsigned short* h2g = h1g + (size_t)4096 * 512;        // 4096*128 fp16

    build_nbr_kernel<<<N_NODES, 256, 0, stream>>>(adj, nbr, cnt, as1, ad1, as2, ad2);

    // layer 1: h1 = x @ w1 (fp16 shadow + fused scores)
    sgemm_att_kernel<64, 64, 32, 4, 4, 8>
        <<<dim3(512 / 64, 4096 / 64), 256, 0, stream>>>(
        x, w1, h1g, att_src1, att_dst1, as1, ad1, 4096, 512, 256);
    attn1_kernel<<<N_NODES, 128, 0, stream>>>(h1g, as1, ad1, nbr, cnt, b1, out1);

    // layer 2: h2 = out1 @ w2 (fp16 shadow + fused scores)
    sgemm_att_kernel<32, 64, 32, 2, 4, 1>
        <<<dim3(128 / 64, 4096 / 32), 256, 0, stream>>>(
        out1, w2, h2g, att_src2, att_dst2, as2, ad2, 4096, 128, 512);
    attn2_kernel<<<N_NODES / 2, 128, 0, stream>>>(h2g, as2, ad2, nbr, cnt, b2, out);
}

// Round 7
// 226.372 us; speedup vs baseline: 1.1516x; 1.1110x over previous
//
#include <hip/hip_runtime.h>
#include <hip/hip_bf16.h>
#include <cstdint>

#define N_NODES 4096
#define STRIDE  384      // max degree (Binom(4096,0.05) ~205 mean, 12-sigma cap)
#define NPAIRS_MAX 192   // STRIDE/2
#define WP1     196      // padded pair-dim: 196%32=4 -> head rows on distinct banks
#define QMAX    128      // per-quarter degree cap in build_nbr

typedef _Float16 half2v __attribute__((ext_vector_type(2)));

// ---- fp16 helpers ---------------------------------------------------------
__device__ __forceinline__ unsigned pkrtz(float a, float b) {   // (lo=a, hi=b)
    return __builtin_bit_cast(unsigned, __builtin_amdgcn_cvt_pkrtz(a, b));
}
__device__ __forceinline__ float f16lo(unsigned u) {
    half2v h = __builtin_bit_cast(half2v, u); return (float)h.x;
}
__device__ __forceinline__ float f16hi(unsigned u) {
    half2v h = __builtin_bit_cast(half2v, u); return (float)h.y;
}
// (a.lo16, b.lo16) and (a.hi16, b.hi16)
__device__ __forceinline__ unsigned pk_lo(unsigned a, unsigned b) {
    return __builtin_amdgcn_perm(b, a, 0x05040100u);
}
__device__ __forceinline__ unsigned pk_hi(unsigned a, unsigned b) {
    return __builtin_amdgcn_perm(b, a, 0x07060302u);
}
__device__ __forceinline__ float fdot2f(unsigned v, unsigned w, float acc) {
    return __builtin_amdgcn_fdot2(__builtin_bit_cast(half2v, v),
                                  __builtin_bit_cast(half2v, w), acc, false);
}
__device__ __forceinline__ float lrelu02(float s) { return (s > 0.f) ? s : 0.2f * s; }
__device__ __forceinline__ float lrelu01(float s) { return (s > 0.f) ? s : 0.01f * s; }

// ---------------------------------------------------------------------------
// 1. Neighbor-list compaction (4 waves/row) + zero-init of score accumulators.
// ---------------------------------------------------------------------------
__global__ __launch_bounds__(256) void build_nbr_kernel(
    const float* __restrict__ adj, unsigned short* __restrict__ nbr,
    int* __restrict__ cnt, float* __restrict__ as1, float* __restrict__ ad1,
    float* __restrict__ as2, float* __restrict__ ad2) {
    const int i    = blockIdx.x;
    const int tid  = threadIdx.x;
    const int wv   = tid >> 6;
    const int lane = tid & 63;
    if (tid < 8)  { as1[i * 8 + tid] = 0.f; ad1[i * 8 + tid] = 0.f; }
    if (tid == 8) { as2[i] = 0.f; }
    if (tid == 9) { ad2[i] = 0.f; }
    __shared__ unsigned short s_buf[4][QMAX];
    __shared__ int s_cnt[4];
    const float4* row = (const float4*)(adj + (size_t)i * N_NODES);
    int base = 0;
#pragma unroll
    for (int it = 0; it < 4; it++) {
        float4 v = row[wv * 256 + it * 64 + lane];
        float e4[4] = {v.x, v.y, v.z, v.w};
        unsigned long long m4[4];
#pragma unroll
        for (int e = 0; e < 4; e++) m4[e] = __ballot(e4[e] != 0.0f);
#pragma unroll
        for (int e = 0; e < 4; e++) {
            int prefix = __popcll(m4[e] & ((1ull << lane) - 1ull));
            int pos = base + prefix;
            if (e4[e] != 0.0f && pos < QMAX)
                s_buf[wv][pos] = (unsigned short)(wv * 1024 + (it * 64 + lane) * 4 + e);
            base += __popcll(m4[e]);
        }
    }
    if (lane == 0) s_cnt[wv] = (base < QMAX) ? base : QMAX;
    __syncthreads();
    const int c0 = s_cnt[0], c1 = s_cnt[1], c2 = s_cnt[2], c3 = s_cnt[3];
    const int o1 = c0, o2 = c0 + c1, o3 = o2 + c2;
    int total = o3 + c3;
    if (total > STRIDE) total = STRIDE;
    for (int k = tid; k < total; k += 256) {
        int w, loc;
        if      (k < o1) { w = 0; loc = k; }
        else if (k < o2) { w = 1; loc = k - o1; }
        else if (k < o3) { w = 2; loc = k - o2; }
        else             { w = 3; loc = k - o3; }
        nbr[(size_t)i * STRIDE + k] = s_buf[w][loc];
    }
    if (tid == 0) cnt[i] = total;
}

// ---------------------------------------------------------------------------
// 2. Tiled fp32 GEMM, fused epilogue: fp16 C + atomic per-row score partials.
// ---------------------------------------------------------------------------
template<int BM, int BN, int BK, int TM, int TN, int H>
__global__ __launch_bounds__(256) void sgemm_att_kernel(
    const float* __restrict__ A, const float* __restrict__ B,
    unsigned short* __restrict__ C16,
    const float* __restrict__ att_s, const float* __restrict__ att_d,
    float* __restrict__ as_, float* __restrict__ ad_,
    int M, int N, int K) {
    static_assert((BM / TM) * (BN / TN) == 256, "256 threads");
    static_assert(TN == 4, "epilogue assumes TN=4");
    __shared__ float As[BK][BM + 4];
    __shared__ float Bs[BK][BN + 4];
    const int tid  = threadIdx.x;
    const int tx   = tid % (BN / TN);
    const int ty   = tid / (BN / TN);
    const int row0 = blockIdx.y * BM;
    const int col0 = blockIdx.x * BN;
    float acc[TM][TN] = {};
    for (int k0 = 0; k0 < K; k0 += BK) {
        for (int i = tid; i < BM * BK / 4; i += 256) {
            int r  = i / (BK / 4);
            int kq = i % (BK / 4);
            float4 v = *(const float4*)(A + (size_t)(row0 + r) * K + k0 + kq * 4);
            As[kq * 4 + 0][r] = v.x;
            As[kq * 4 + 1][r] = v.y;
            As[kq * 4 + 2][r] = v.z;
            As[kq * 4 + 3][r] = v.w;
        }
        for (int i = tid; i < BK * BN / 4; i += 256) {
            int r  = i / (BN / 4);
            int cq = i % (BN / 4);
            *(float4*)&Bs[r][cq * 4] =
                *(const float4*)(B + (size_t)(k0 + r) * N + col0 + cq * 4);
        }
        __syncthreads();
#pragma unroll
        for (int kk = 0; kk < BK; kk++) {
            float a[TM], b[TN];
#pragma unroll
            for (int t = 0; t < TM; t++) a[t] = As[kk][ty * TM + t];
#pragma unroll
            for (int u = 0; u < TN; u++) b[u] = Bs[kk][tx * TN + u];
#pragma unroll
            for (int t = 0; t < TM; t++)
#pragma unroll
                for (int u = 0; u < TN; u++) acc[t][u] += a[t] * b[u];
        }
        __syncthreads();
    }
    float asv[TN], adv[TN];
#pragma unroll
    for (int u = 0; u < TN; u++) {
        asv[u] = att_s[col0 + tx * TN + u];
        adv[u] = att_d[col0 + tx * TN + u];
    }
    const int head = (H > 1) ? (col0 >> 6) : 0;
#pragma unroll
    for (int t = 0; t < TM; t++) {
        const int row = row0 + ty * TM + t;
        uint2 pk;
        pk.x = pkrtz(acc[t][0], acc[t][1]);
        pk.y = pkrtz(acc[t][2], acc[t][3]);
        *(uint2*)(C16 + (size_t)row * N + col0 + tx * TN) = pk;
        float ps = 0.f, pd = 0.f;
#pragma unroll
        for (int u = 0; u < TN; u++) { ps += acc[t][u] * asv[u]; pd += acc[t][u] * adv[u]; }
#pragma unroll
        for (int off = 8; off; off >>= 1) {
            ps += __shfl_xor(ps, off);
            pd += __shfl_xor(pd, off);
        }
        if (tx == 0) {
            atomicAdd(&as_[row * H + head], ps);
            atomicAdd(&ad_[row * H + head], pd);
        }
    }
}

// ---------------------------------------------------------------------------
// 3. Layer-1 sparse aggregate: ONE WAVE per row (lane owns 8 channels), 128-thr
//    block = 2 rows, zero barriers. Weights computed in-wave edge-parallel
//    (16B asrc gathers), packed fp16 pairs in LDS. Pass 3: one dwordx4 per
//    EDGE fetches the full 1KB fp16 row; fdot2 accumulation over edge pairs.
// ---------------------------------------------------------------------------
__global__ __launch_bounds__(128) void attn1_kernel(
    const unsigned short* __restrict__ h1g, const float* __restrict__ asrc,
    const float* __restrict__ adst, const unsigned short* __restrict__ nbr,
    const int* __restrict__ cnt, const float* __restrict__ b1,
    float* __restrict__ out1) {
    const int wv   = threadIdx.x >> 6;
    const int i    = blockIdx.x * 2 + wv;      // row
    const int lane = threadIdx.x & 63;
    __shared__ __align__(16) unsigned s_wp[2][8][WP1];   // fp16 weight pairs
    __shared__ __align__(16) unsigned s_nb[2][NPAIRS_MAX];
    __shared__ float s_inv[2][8];

    const int n      = cnt[i];
    const int npairs = (n + 1) >> 1;
    const int nq     = (npairs + 3) >> 2;      // pair-quads
    const int npadp  = nq * 4;                 // padded pairs
    const int npadE  = npadp * 2;              // padded edges

    // stage neighbor pairs (masked: hi of odd tail + pad pairs -> 0)
    const unsigned* nbr32 = (const unsigned*)(nbr + (size_t)i * STRIDE);
    for (int k = lane; k < npadp; k += 64) {
        unsigned v = 0u;
        if (2 * k + 1 < n)      v = nbr32[k];
        else if (2 * k < n)     v = nbr32[k] & 0xffffu;
        s_nb[wv][k] = v;
    }

    // phase A: edge-parallel score max (lane = edge), 8 heads in registers
    float ad8[8];
    {
        const float4 a0 = *(const float4*)(adst + i * 8);
        const float4 a1 = *(const float4*)(adst + i * 8 + 4);
        ad8[0]=a0.x; ad8[1]=a0.y; ad8[2]=a0.z; ad8[3]=a0.w;
        ad8[4]=a1.x; ad8[5]=a1.y; ad8[6]=a1.z; ad8[7]=a1.w;
    }
    float m8[8];
#pragma unroll
    for (int k = 0; k < 8; k++) m8[k] = -1e30f;
    for (int e = lane; e < n; e += 64) {
        const int id = (s_nb[wv][e >> 1] >> ((e & 1) * 16)) & 0xffff;
        const float4 q0 = *(const float4*)(asrc + id * 8);
        const float4 q1 = *(const float4*)(asrc + id * 8 + 4);
        const float sv[8] = {q0.x, q0.y, q0.z, q0.w, q1.x, q1.y, q1.z, q1.w};
#pragma unroll
        for (int k = 0; k < 8; k++) m8[k] = fmaxf(m8[k], lrelu02(sv[k] + ad8[k]));
    }
#pragma unroll
    for (int k = 0; k < 8; k++)
#pragma unroll
        for (int off = 32; off; off >>= 1) m8[k] = fmaxf(m8[k], __shfl_xor(m8[k], off));

    // phase B: re-gather (L1-hot), exp, pack fp16 into per-head LDS rows;
    // denominator from the ROUNDED fp16 weights (bias cancels at normalize).
    float l8[8];
#pragma unroll
    for (int k = 0; k < 8; k++) l8[k] = 0.f;
    unsigned short* wrow = (unsigned short*)&s_wp[wv][0][0];   // head stride 392 u16
    for (int e = lane; e < npadE; e += 64) {
        if (e < n) {
            const int id = (s_nb[wv][e >> 1] >> ((e & 1) * 16)) & 0xffff;
            const float4 q0 = *(const float4*)(asrc + id * 8);
            const float4 q1 = *(const float4*)(asrc + id * 8 + 4);
            const float sv[8] = {q0.x, q0.y, q0.z, q0.w, q1.x, q1.y, q1.z, q1.w};
#pragma unroll
            for (int k = 0; k < 8; k++) {
                float ev = __expf(lrelu02(sv[k] + ad8[k]) - m8[k]);
                unsigned h16 = pkrtz(ev, 0.f) & 0xffffu;
                l8[k] += f16lo(h16);
                wrow[k * (WP1 * 2) + e] = (unsigned short)h16;
            }
        } else {
#pragma unroll
            for (int k = 0; k < 8; k++) wrow[k * (WP1 * 2) + e] = 0;
        }
    }
#pragma unroll
    for (int k = 0; k < 8; k++) {
#pragma unroll
        for (int off = 32; off; off >>= 1) l8[k] += __shfl_xor(l8[k], off);
        if (lane == 0) s_inv[wv][k] = 1.0f / l8[k];
    }

    // phase C: full-row gather. lane owns channels lane*8..lane*8+7
    const int hd = lane >> 3;                       // head of this lane
    const char* hb = (const char*)h1g + lane * 16;  // +16B per lane
    float ac[8] = {};
    for (int q = 0; q < nq; q++) {
        const uint4 idq = *(const uint4*)&s_nb[wv][q * 4];
        const uint4 wq  = *(const uint4*)&s_wp[wv][hd][q * 4];
        const unsigned idv[4] = {idq.x, idq.y, idq.z, idq.w};
        const unsigned wv4[4] = {wq.x, wq.y, wq.z, wq.w};
#pragma unroll
        for (int p = 0; p < 4; p++) {
            const int iA = idv[p] & 0xffff, iB = idv[p] >> 16;
            const uint4 vA = *(const uint4*)(hb + (size_t)iA * 1024);
            const uint4 vB = *(const uint4*)(hb + (size_t)iB * 1024);
            const unsigned w = wv4[p];
            ac[0] = fdot2f(pk_lo(vA.x, vB.x), w, ac[0]);
            ac[1] = fdot2f(pk_hi(vA.x, vB.x), w, ac[1]);
            ac[2] = fdot2f(pk_lo(vA.y, vB.y), w, ac[2]);
            ac[3] = fdot2f(pk_hi(vA.y, vB.y), w, ac[3]);
            ac[4] = fdot2f(pk_lo(vA.z, vB.z), w, ac[4]);
            ac[5] = fdot2f(pk_hi(vA.z, vB.z), w, ac[5]);
            ac[6] = fdot2f(pk_lo(vA.w, vB.w), w, ac[6]);
            ac[7] = fdot2f(pk_hi(vA.w, vB.w), w, ac[7]);
        }
    }
    const float inv = s_inv[wv][hd];
    const float4 bb0 = *(const float4*)(b1 + lane * 8);
    const float4 bb1 = *(const float4*)(b1 + lane * 8 + 4);
    float4 o0, o1;
    o0.x = lrelu01(ac[0] * inv + bb0.x);
    o0.y = lrelu01(ac[1] * inv + bb0.y);
    o0.z = lrelu01(ac[2] * inv + bb0.z);
    o0.w = lrelu01(ac[3] * inv + bb0.w);
    o1.x = lrelu01(ac[4] * inv + bb1.x);
    o1.y = lrelu01(ac[5] * inv + bb1.y);
    o1.z = lrelu01(ac[6] * inv + bb1.z);
    o1.w = lrelu01(ac[7] * inv + bb1.w);
    *(float4*)(out1 + (size_t)i * 512 + lane * 8)     = o0;
    *(float4*)(out1 + (size_t)i * 512 + lane * 8 + 4) = o1;
}

// ---------------------------------------------------------------------------
// 4. Layer-2 sparse aggregate: one wave per row; 2 edges per gather inst
//    (lanes 0-31 = edge A, 32-63 = edge B; each lane 4 channels = 8B).
// ---------------------------------------------------------------------------
__global__ __launch_bounds__(128) void attn2_kernel(
    const unsigned short* __restrict__ h2g, const float* __restrict__ asrc,
    const float* __restrict__ adst, const unsigned short* __restrict__ nbr,
    const int* __restrict__ cnt, const float* __restrict__ b2,
    float* __restrict__ out) {
    const int wv   = threadIdx.x >> 6;
    const int i    = blockIdx.x * 2 + wv;
    const int lane = threadIdx.x & 63;
    __shared__ __align__(16) unsigned s_wp[2][WP1];
    __shared__ __align__(16) unsigned s_nb[2][NPAIRS_MAX];

    const int n      = cnt[i];
    const int npairs = (n + 1) >> 1;
    const int nq     = (npairs + 3) >> 2;
    const int npadp  = nq * 4;
    const int npadE  = npadp * 2;

    const unsigned* nbr32 = (const unsigned*)(nbr + (size_t)i * STRIDE);
    for (int k = lane; k < npadp; k += 64) {
        unsigned v = 0u;
        if (2 * k + 1 < n)      v = nbr32[k];
        else if (2 * k < n)     v = nbr32[k] & 0xffffu;
        s_nb[wv][k] = v;
    }

    // weights (single head): scores kept in registers across iters (<=6)
    const float ad = adst[i];
    float sreg[6];
    float m = -1e30f;
    const int niter = (npadE + 63) >> 6;
#pragma unroll 6
    for (int it = 0; it < niter; it++) {
        const int e = it * 64 + lane;
        float s = -1e30f;
        if (e < n) {
            const int id = (s_nb[wv][e >> 1] >> ((e & 1) * 16)) & 0xffff;
            s = lrelu02(asrc[id] + ad);
        }
        sreg[it] = s;
        m = fmaxf(m, s);
    }
#pragma unroll
    for (int off = 32; off; off >>= 1) m = fmaxf(m, __shfl_xor(m, off));
    float l = 0.f;
    unsigned short* wrow = (unsigned short*)&s_wp[wv][0];
#pragma unroll 6
    for (int it = 0; it < niter; it++) {
        const int e = it * 64 + lane;
        if (e < npadE) {
            unsigned h16 = 0u;
            if (e < n) {
                float ev = __expf(sreg[it] - m);
                h16 = pkrtz(ev, 0.f) & 0xffffu;
                l += f16lo(h16);
            }
            wrow[e] = (unsigned short)h16;
        }
    }
#pragma unroll
    for (int off = 32; off; off >>= 1) l += __shfl_xor(l, off);
    const float inv = 1.0f / l;

    // gather: lane<32 -> edge A, lane>=32 -> edge B; lane owns 4 channels
    const bool hiE = lane >= 32;
    const char* hb = (const char*)h2g + (lane & 31) * 8;   // 4 ch fp16 = 8B
    float a0 = 0.f, a1 = 0.f, a2 = 0.f, a3 = 0.f;
    for (int q = 0; q < nq; q++) {
        const uint4 idq = *(const uint4*)&s_nb[wv][q * 4];
        const uint4 wq  = *(const uint4*)&s_wp[wv][q * 4];
        const unsigned idv[4] = {idq.x, idq.y, idq.z, idq.w};
        const unsigned wv4[4] = {wq.x, wq.y, wq.z, wq.w};
#pragma unroll
        for (int p = 0; p < 4; p++) {
            const unsigned id = hiE ? (idv[p] >> 16) : (idv[p] & 0xffffu);
            const float w = hiE ? f16hi(wv4[p]) : f16lo(wv4[p]);
            const uint2 v = *(const uint2*)(hb + (size_t)id * 256);
            a0 += w * f16lo(v.x);
            a1 += w * f16hi(v.x);
            a2 += w * f16lo(v.y);
            a3 += w * f16hi(v.y);
        }
    }
    a0 += __shfl_xor(a0, 32);
    a1 += __shfl_xor(a1, 32);
    a2 += __shfl_xor(a2, 32);
    a3 += __shfl_xor(a3, 32);
    if (lane < 32) {
        const float4 bb = *(const float4*)(b2 + lane * 4);
        float4 o;
        o.x = lrelu01(a0 * inv + bb.x);
        o.y = lrelu01(a1 * inv + bb.y);
        o.z = lrelu01(a2 * inv + bb.z);
        o.w = lrelu01(a3 * inv + bb.w);
        *(float4*)(out + (size_t)i * 128 + lane * 4) = o;
    }
}

// ---------------------------------------------------------------------------
extern "C" void kernel_launch(void* const* d_in, const int* in_sizes, int n_in,
                              void* d_out, int out_size, void* d_ws, size_t ws_size,
                              hipStream_t stream) {
    const float* x        = (const float*)d_in[0];   // [4096,256]
    const float* adj      = (const float*)d_in[1];   // [4096,4096]
    const float* w1       = (const float*)d_in[2];   // [256,512]
    const float* att_src1 = (const float*)d_in[3];   // [8,64]
    const float* att_dst1 = (const float*)d_in[4];
    const float* b1       = (const float*)d_in[5];   // [512]
    const float* w2       = (const float*)d_in[6];   // [512,128]
    const float* att_src2 = (const float*)d_in[7];   // [1,128]
    const float* att_dst2 = (const float*)d_in[8];
    const float* b2       = (const float*)d_in[9];   // [128]
    float* out = (float*)d_out;                      // [4096,128]

    float* ws   = (float*)d_ws;
    float* out1 = ws;                               // 4096*512 f
    float* as1  = out1 + 4096 * 512;                // 4096*8 f
    float* ad1  = as1 + 4096 * 8;                   // 4096*8 f
    float* as2  = ad1 + 4096 * 8;                   // 4096 f
    float* ad2  = as2 + 4096;                       // 4096 f
    int*   cnt  = (int*)(ad2 + 4096);               // 4096 i32
    unsigned short* nbr = (unsigned short*)(cnt + 4096);   // 4096*STRIDE u16
    unsigned short* h1g = nbr + (size_t)4096 * STRIDE;     // 4096*512 fp16
    unsigned short* h2g = h1g + (size_t)4096 * 512;        // 4096*128 fp16

    build_nbr_kernel<<<N_NODES, 256, 0, stream>>>(adj, nbr, cnt, as1, ad1, as2, ad2);

    // layer 1: h1 = x @ w1 (fp16 shadow + fused scores)
    sgemm_att_kernel<64, 64, 32, 4, 4, 8>
        <<<dim3(512 / 64, 4096 / 64), 256, 0, stream>>>(
        x, w1, h1g, att_src1, att_dst1, as1, ad1, 4096, 512, 256);
    attn1_kernel<<<N_NODES / 2, 128, 0, stream>>>(h1g, as1, ad1, nbr, cnt, b1, out1);

    // layer 2: h2 = out1 @ w2 (fp16 shadow + fused scores)
    sgemm_att_kernel<32, 64, 32, 2, 4, 1>
        <<<dim3(128 / 64, 4096 / 32), 256, 0, stream>>>(
        out1, w2, h2g, att_src2, att_dst2, as2, ad2, 4096, 128, 512);
    attn2_kernel<<<N_NODES / 2, 128, 0, stream>>>(h2g, as2, ad2, nbr, cnt, b2, out);
}

// Round 8
// 217.009 us; speedup vs baseline: 1.2013x; 1.0431x over previous
//
#include <hip/hip_runtime.h>
#include <hip/hip_bf16.h>
#include <cstdint>

#define N_NODES 4096
#define STRIDE  384      // max degree cap (Binom(4096,0.05): mean 205, 12 sigma)
#define NPAIRS_MAX 192
#define QMAX    128      // per-quarter degree cap in build_nbr
#define WROW    400      // s_w16 head-row stride (u16): 200 words, %32=8 -> 2-way max

typedef _Float16 half2v __attribute__((ext_vector_type(2)));
typedef _Float16 v4h __attribute__((ext_vector_type(4)));
typedef _Float16 v8h __attribute__((ext_vector_type(8)));
typedef float    v4f __attribute__((ext_vector_type(4)));

// ---- fp16 helpers ---------------------------------------------------------
__device__ __forceinline__ float f16lo(unsigned u) {
    half2v h = __builtin_bit_cast(half2v, u); return (float)h.x;
}
__device__ __forceinline__ float f16hi(unsigned u) {
    half2v h = __builtin_bit_cast(half2v, u); return (float)h.y;
}
// (a.lo16, b.lo16) / (a.hi16, b.hi16)
__device__ __forceinline__ unsigned pk_lo(unsigned a, unsigned b) {
    return __builtin_amdgcn_perm(b, a, 0x05040100u);
}
__device__ __forceinline__ unsigned pk_hi(unsigned a, unsigned b) {
    return __builtin_amdgcn_perm(b, a, 0x07060302u);
}
__device__ __forceinline__ float fdot2f(unsigned v, unsigned w, float acc) {
    return __builtin_amdgcn_fdot2(__builtin_bit_cast(half2v, v),
                                  __builtin_bit_cast(half2v, w), acc, false);
}
__device__ __forceinline__ float lrelu02(float s) { return (s > 0.f) ? s : 0.2f * s; }
__device__ __forceinline__ float lrelu01(float s) { return (s > 0.f) ? s : 0.01f * s; }

// ---------------------------------------------------------------------------
// 1. Neighbor-list compaction (4 waves/row).
// ---------------------------------------------------------------------------
__global__ __launch_bounds__(256) void build_nbr_kernel(
    const float* __restrict__ adj, unsigned short* __restrict__ nbr,
    int* __restrict__ cnt) {
    const int i    = blockIdx.x;
    const int tid  = threadIdx.x;
    const int wv   = tid >> 6;
    const int lane = tid & 63;
    __shared__ unsigned short s_buf[4][QMAX];
    __shared__ int s_cnt[4];
    const float4* row = (const float4*)(adj + (size_t)i * N_NODES);
    int base = 0;
#pragma unroll
    for (int it = 0; it < 4; it++) {
        float4 v = row[wv * 256 + it * 64 + lane];
        float e4[4] = {v.x, v.y, v.z, v.w};
        unsigned long long m4[4];
#pragma unroll
        for (int e = 0; e < 4; e++) m4[e] = __ballot(e4[e] != 0.0f);
#pragma unroll
        for (int e = 0; e < 4; e++) {
            int prefix = __popcll(m4[e] & ((1ull << lane) - 1ull));
            int pos = base + prefix;
            if (e4[e] != 0.0f && pos < QMAX)
                s_buf[wv][pos] = (unsigned short)(wv * 1024 + (it * 64 + lane) * 4 + e);
            base += __popcll(m4[e]);
        }
    }
    if (lane == 0) s_cnt[wv] = (base < QMAX) ? base : QMAX;
    __syncthreads();
    const int c0 = s_cnt[0], c1 = s_cnt[1], c2 = s_cnt[2], c3 = s_cnt[3];
    const int o1 = c0, o2 = c0 + c1, o3 = o2 + c2;
    int total = o3 + c3;
    if (total > STRIDE) total = STRIDE;
    for (int k = tid; k < total; k += 256) {
        int w, loc;
        if      (k < o1) { w = 0; loc = k; }
        else if (k < o2) { w = 1; loc = k - o1; }
        else if (k < o3) { w = 2; loc = k - o2; }
        else             { w = 3; loc = k - o3; }
        nbr[(size_t)i * STRIDE + k] = s_buf[w][loc];
    }
    if (tid == 0) cnt[i] = total;
}

// ---------------------------------------------------------------------------
// 2. Prep: x -> fp16 (RNE); w1,w2 -> transposed fp16 (wT[n][k]).
// ---------------------------------------------------------------------------
__global__ __launch_bounds__(256) void prep_kernel(
    const float* __restrict__ x, const float* __restrict__ w1,
    const float* __restrict__ w2, _Float16* __restrict__ x16,
    _Float16* __restrict__ w1T, _Float16* __restrict__ w2T) {
    const int b = blockIdx.x, t = threadIdx.x;
    if (b < 1024) {                       // x: 4096*256 = 1M elems, 4/thread
        const int idx = b * 1024 + t * 4;
        float4 v = *(const float4*)(x + idx);
        v4h h = { (_Float16)v.x, (_Float16)v.y, (_Float16)v.z, (_Float16)v.w };
        *(v4h*)(x16 + idx) = h;
    } else if (b < 1536) {                // w1T[512][256] <- w1[256][512]
        const int idx = (b - 1024) * 256 + t;
        const int n = idx >> 8, k = idx & 255;
        w1T[idx] = (_Float16)w1[k * 512 + n];
    } else {                              // w2T[128][512] <- w2[512][128]
        const int idx = (b - 1536) * 256 + t;
        const int n = idx >> 9, k = idx & 511;
        w2T[idx] = (_Float16)w2[k * 128 + n];
    }
}

// ---------------------------------------------------------------------------
// 3. MFMA GEMM: C[M,N] = A[M,K] @ B[K,N], fp16 in / fp32 accum.
//    One wave computes a 16 x (16*NSUB) strip over full K.
//    Verified layouts: A[m=lane&15][k=quad*8+j]; B[k=quad*8+j][n=lane&15]
//    (loaded from BT16[n][k], contiguous 16B); D[row=quad*4+r][col=lane&15].
//    Epilogue: fp16 C store + DIRECT (non-atomic) per-row score writes:
//    each (row, head) is covered by exactly one wave.
// ---------------------------------------------------------------------------
template<int KCH, int NSUB, int H>
__global__ __launch_bounds__(256) void gemm_mfma_kernel(
    const _Float16* __restrict__ A16, const _Float16* __restrict__ BT16,
    _Float16* __restrict__ C16,
    const float* __restrict__ att_s, const float* __restrict__ att_d,
    float* __restrict__ as_, float* __restrict__ ad_, int N) {
    const int K    = KCH * 32;
    const int wid  = blockIdx.x * 4 + (threadIdx.x >> 6);
    const int lane = threadIdx.x & 63;
    const int quad = lane >> 4, l16 = lane & 15;
    const int ntiles = N / (16 * NSUB);
    const int m0 = (wid / ntiles) * 16;
    const int n0 = (wid % ntiles) * (16 * NSUB);

    v8h a[KCH];
    const v8h* arow = (const v8h*)(A16 + (size_t)(m0 + l16) * K + quad * 8);
#pragma unroll
    for (int c = 0; c < KCH; c++) a[c] = arow[c * 4];

    float ps[4] = {}, pd[4] = {};
#pragma unroll
    for (int s = 0; s < NSUB; s++) {
        const int n = n0 + s * 16 + l16;
        const v8h* brow = (const v8h*)(BT16 + (size_t)n * K + quad * 8);
        v4f acc = {0.f, 0.f, 0.f, 0.f};
#pragma unroll
        for (int c = 0; c < KCH; c++)
            acc = __builtin_amdgcn_mfma_f32_16x16x32_f16(a[c], brow[c * 4], acc, 0, 0, 0);
        const float sa = att_s[n], sd = att_d[n];
#pragma unroll
        for (int r = 0; r < 4; r++) {
            C16[(size_t)(m0 + quad * 4 + r) * N + n] = (_Float16)acc[r];
            ps[r] += acc[r] * sa;
            pd[r] += acc[r] * sd;
        }
    }
#pragma unroll
    for (int r = 0; r < 4; r++) {
#pragma unroll
        for (int off = 1; off < 16; off <<= 1) {
            ps[r] += __shfl_xor(ps[r], off);
            pd[r] += __shfl_xor(pd[r], off);
        }
    }
    if (l16 == 0) {
        const int head = (H > 1) ? (n0 >> 6) : 0;
#pragma unroll
        for (int r = 0; r < 4; r++) {
            const int row = m0 + quad * 4 + r;
            as_[row * H + head] = ps[r];
            ad_[row * H + head] = pd[r];
        }
    }
}

// ---------------------------------------------------------------------------
// 4. Layer-1 sparse aggregate: one 2-wave block per row. Both waves compute
//    scores/weights (redundant, cheap, no barrier); pass-3 edge-quads split
//    by parity; one barrier + LDS combine; wave1 does the epilogue and
//    writes out1 in fp16 (GEMM2's A operand).
// ---------------------------------------------------------------------------
__global__ __launch_bounds__(128) void attn1_kernel(
    const _Float16* __restrict__ h1g, const float* __restrict__ asrc,
    const float* __restrict__ adst, const unsigned short* __restrict__ nbr,
    const int* __restrict__ cnt, const float* __restrict__ b1,
    _Float16* __restrict__ out1f16) {
    const int i    = blockIdx.x;
    const int wv   = threadIdx.x >> 6;
    const int lane = threadIdx.x & 63;
    const int hd   = lane >> 3;               // head of this lane (8 ch each)
    __shared__ __align__(16) unsigned s_nb[NPAIRS_MAX];
    __shared__ __align__(16) unsigned short s_w16[8][WROW];
    __shared__ __align__(16) float s_comb[512];

    const int n      = cnt[i];
    const int npairs = (n + 1) >> 1;
    const int nq     = (npairs + 3) >> 2;     // pair-quads (8 edges each)
    const int npadp  = nq * 4;
    const int npadE  = npadp * 2;

    // stage neighbor pairs (both waves duplicate-write identical values)
    const unsigned* nbr32 = (const unsigned*)(nbr + (size_t)i * STRIDE);
    for (int k = lane; k < npadp; k += 64) {
        unsigned v = 0u;
        if (2 * k + 1 < n)  v = nbr32[k];
        else if (2 * k < n) v = nbr32[k] & 0xffffu;
        s_nb[k] = v;
    }

    float ad8[8];
    {
        const float4 a0 = *(const float4*)(adst + i * 8);
        const float4 a1 = *(const float4*)(adst + i * 8 + 4);
        ad8[0]=a0.x; ad8[1]=a0.y; ad8[2]=a0.z; ad8[3]=a0.w;
        ad8[4]=a1.x; ad8[5]=a1.y; ad8[6]=a1.z; ad8[7]=a1.w;
    }
    // phase A: per-head max
    float m8[8];
#pragma unroll
    for (int k = 0; k < 8; k++) m8[k] = -1e30f;
    for (int e = lane; e < n; e += 64) {
        const int id = (s_nb[e >> 1] >> ((e & 1) * 16)) & 0xffff;
        const float4 q0 = *(const float4*)(asrc + id * 8);
        const float4 q1 = *(const float4*)(asrc + id * 8 + 4);
        const float sv[8] = {q0.x, q0.y, q0.z, q0.w, q1.x, q1.y, q1.z, q1.w};
#pragma unroll
        for (int k = 0; k < 8; k++) m8[k] = fmaxf(m8[k], lrelu02(sv[k] + ad8[k]));
    }
#pragma unroll
    for (int k = 0; k < 8; k++)
#pragma unroll
        for (int off = 32; off; off >>= 1) m8[k] = fmaxf(m8[k], __shfl_xor(m8[k], off));

    // phase B: exp (RNE to fp16), weights -> LDS, denominator from rounded w
    float l8[8];
#pragma unroll
    for (int k = 0; k < 8; k++) l8[k] = 0.f;
    for (int e = lane; e < npadE; e += 64) {
        if (e < n) {
            const int id = (s_nb[e >> 1] >> ((e & 1) * 16)) & 0xffff;
            const float4 q0 = *(const float4*)(asrc + id * 8);
            const float4 q1 = *(const float4*)(asrc + id * 8 + 4);
            const float sv[8] = {q0.x, q0.y, q0.z, q0.w, q1.x, q1.y, q1.z, q1.w};
#pragma unroll
            for (int k = 0; k < 8; k++) {
                float ev = __expf(lrelu02(sv[k] + ad8[k]) - m8[k]);
                _Float16 h = (_Float16)ev;
                l8[k] += (float)h;
                s_w16[k][e] = __builtin_bit_cast(unsigned short, h);
            }
        } else {
#pragma unroll
            for (int k = 0; k < 8; k++) s_w16[k][e] = 0;
        }
    }
#pragma unroll
    for (int k = 0; k < 8; k++)
#pragma unroll
        for (int off = 32; off; off >>= 1) l8[k] += __shfl_xor(l8[k], off);

    // pass 3: full-row gather (lane owns channels lane*8..+7), quads split
    // by wave parity. Per pair: 2x dwordx4 + 8 perm + 8 fdot2.
    const char* hb = (const char*)h1g + lane * 16;
    float ac[8] = {};
    for (int q = wv; q < nq; q += 2) {
        const uint4 idq = *(const uint4*)&s_nb[q * 4];
        const uint4 wq  = *(const uint4*)((const unsigned*)&s_w16[hd][0] + q * 4);
        const unsigned idv[4] = {idq.x, idq.y, idq.z, idq.w};
        const unsigned wv4[4] = {wq.x, wq.y, wq.z, wq.w};
#pragma unroll
        for (int p = 0; p < 4; p++) {
            const int iA = idv[p] & 0xffff, iB = idv[p] >> 16;
            const uint4 vA = *(const uint4*)(hb + (size_t)iA * 1024);
            const uint4 vB = *(const uint4*)(hb + (size_t)iB * 1024);
            const unsigned w = wv4[p];
            ac[0] = fdot2f(pk_lo(vA.x, vB.x), w, ac[0]);
            ac[1] = fdot2f(pk_hi(vA.x, vB.x), w, ac[1]);
            ac[2] = fdot2f(pk_lo(vA.y, vB.y), w, ac[2]);
            ac[3] = fdot2f(pk_hi(vA.y, vB.y), w, ac[3]);
            ac[4] = fdot2f(pk_lo(vA.z, vB.z), w, ac[4]);
            ac[5] = fdot2f(pk_hi(vA.z, vB.z), w, ac[5]);
            ac[6] = fdot2f(pk_lo(vA.w, vB.w), w, ac[6]);
            ac[7] = fdot2f(pk_hi(vA.w, vB.w), w, ac[7]);
        }
    }
    if (wv == 0) {
        *(float4*)&s_comb[lane * 8]     = make_float4(ac[0], ac[1], ac[2], ac[3]);
        *(float4*)&s_comb[lane * 8 + 4] = make_float4(ac[4], ac[5], ac[6], ac[7]);
    }
    __syncthreads();
    if (wv == 1) {
        const float4 c0 = *(const float4*)&s_comb[lane * 8];
        const float4 c1 = *(const float4*)&s_comb[lane * 8 + 4];
        ac[0] += c0.x; ac[1] += c0.y; ac[2] += c0.z; ac[3] += c0.w;
        ac[4] += c1.x; ac[5] += c1.y; ac[6] += c1.z; ac[7] += c1.w;
        float lv = (hd < 4)
            ? ((hd < 2) ? (hd == 0 ? l8[0] : l8[1]) : (hd == 2 ? l8[2] : l8[3]))
            : ((hd < 6) ? (hd == 4 ? l8[4] : l8[5]) : (hd == 6 ? l8[6] : l8[7]));
        const float inv = 1.0f / lv;
        const float4 bb0 = *(const float4*)(b1 + lane * 8);
        const float4 bb1 = *(const float4*)(b1 + lane * 8 + 4);
        const float bbv[8] = {bb0.x, bb0.y, bb0.z, bb0.w, bb1.x, bb1.y, bb1.z, bb1.w};
        v8h ov;
#pragma unroll
        for (int c = 0; c < 8; c++)
            ov[c] = (_Float16)lrelu01(ac[c] * inv + bbv[c]);
        *(v8h*)(out1f16 + (size_t)i * 512 + lane * 8) = ov;
    }
}

// ---------------------------------------------------------------------------
// 5. Layer-2 sparse aggregate: one wave per row, 4 edges per gather inst
//    (lane group g=lane>>4 carries edge g; 16 lanes x 16B = full 256B row).
// ---------------------------------------------------------------------------
__global__ __launch_bounds__(128) void attn2_kernel(
    const _Float16* __restrict__ h2g, const float* __restrict__ asrc,
    const float* __restrict__ adst, const unsigned short* __restrict__ nbr,
    const int* __restrict__ cnt, const float* __restrict__ b2,
    float* __restrict__ out) {
    const int wv   = threadIdx.x >> 6;
    const int i    = blockIdx.x * 2 + wv;
    const int lane = threadIdx.x & 63;
    const int grp  = lane >> 4, l16 = lane & 15;
    __shared__ __align__(16) unsigned s_nb[2][NPAIRS_MAX];
    __shared__ __align__(16) unsigned short s_w16[2][STRIDE + 16];

    const int n     = cnt[i];
    const int nq4   = (n + 3) >> 2;           // edge-quads
    const int npad4 = nq4 * 4;
    const int npadp = (npad4 + 1) >> 1;

    const unsigned* nbr32 = (const unsigned*)(nbr + (size_t)i * STRIDE);
    for (int k = lane; k < npadp; k += 64) {
        unsigned v = 0u;
        if (2 * k + 1 < n)  v = nbr32[k];
        else if (2 * k < n) v = nbr32[k] & 0xffffu;
        s_nb[wv][k] = v;
    }

    // weights (single head); scores carried in regs across fixed 6 iters
    const float ad = adst[i];
    float sreg[6];
    float m = -1e30f;
#pragma unroll
    for (int it = 0; it < 6; it++) {
        const int e = it * 64 + lane;
        float s = -1e30f;
        if (e < n) {
            const int id = (s_nb[wv][e >> 1] >> ((e & 1) * 16)) & 0xffff;
            s = lrelu02(asrc[id] + ad);
        }
        sreg[it] = s;
        m = fmaxf(m, s);
    }
#pragma unroll
    for (int off = 32; off; off >>= 1) m = fmaxf(m, __shfl_xor(m, off));
    float l = 0.f;
#pragma unroll
    for (int it = 0; it < 6; it++) {
        const int e = it * 64 + lane;
        if (e < n) {
            float ev = __expf(sreg[it] - m);
            _Float16 h = (_Float16)ev;
            l += (float)h;
            s_w16[wv][e] = __builtin_bit_cast(unsigned short, h);
        }
    }
    if (lane < npad4 - n) s_w16[wv][n + lane] = 0;
#pragma unroll
    for (int off = 32; off; off >>= 1) l += __shfl_xor(l, off);
    const float inv = 1.0f / l;

    // gather: 4 edges per iteration; lane loads 16B (8 ch) of edge `grp`
    const char* hb = (const char*)h2g + l16 * 16;
    float ac[8] = {};
    for (int it = 0; it < nq4; it++) {
        const int e = it * 4 + grp;
        const unsigned pr = s_nb[wv][e >> 1];
        const int id = (e & 1) ? (int)(pr >> 16) : (int)(pr & 0xffffu);
        const float w = (float)((const _Float16*)&s_w16[wv][0])[e];
        const uint4 v = *(const uint4*)(hb + (size_t)id * 256);
        ac[0] += w * f16lo(v.x); ac[1] += w * f16hi(v.x);
        ac[2] += w * f16lo(v.y); ac[3] += w * f16hi(v.y);
        ac[4] += w * f16lo(v.z); ac[5] += w * f16hi(v.z);
        ac[6] += w * f16lo(v.w); ac[7] += w * f16hi(v.w);
    }
#pragma unroll
    for (int c = 0; c < 8; c++) {
        ac[c] += __shfl_xor(ac[c], 16);
        ac[c] += __shfl_xor(ac[c], 32);
    }
    if (lane < 16) {
        const float4 bb0 = *(const float4*)(b2 + lane * 8);
        const float4 bb1 = *(const float4*)(b2 + lane * 8 + 4);
        float4 o0, o1;
        o0.x = lrelu01(ac[0] * inv + bb0.x);
        o0.y = lrelu01(ac[1] * inv + bb0.y);
        o0.z = lrelu01(ac[2] * inv + bb0.z);
        o0.w = lrelu01(ac[3] * inv + bb0.w);
        o1.x = lrelu01(ac[4] * inv + bb1.x);
        o1.y = lrelu01(ac[5] * inv + bb1.y);
        o1.z = lrelu01(ac[6] * inv + bb1.z);
        o1.w = lrelu01(ac[7] * inv + bb1.w);
        *(float4*)(out + (size_t)i * 128 + lane * 8)     = o0;
        *(float4*)(out + (size_t)i * 128 + lane * 8 + 4) = o1;
    }
}

// ---------------------------------------------------------------------------
extern "C" void kernel_launch(void* const* d_in, const int* in_sizes, int n_in,
                              void* d_out, int out_size, void* d_ws, size_t ws_size,
                              hipStream_t stream) {
    const float* x        = (const float*)d_in[0];   // [4096,256]
    const float* adj      = (const float*)d_in[1];   // [4096,4096]
    const float* w1       = (const float*)d_in[2];   // [256,512]
    const float* att_src1 = (const float*)d_in[3];   // [8,64]
    const float* att_dst1 = (const float*)d_in[4];
    const float* b1       = (const float*)d_in[5];   // [512]
    const float* w2       = (const float*)d_in[6];   // [512,128]
    const float* att_src2 = (const float*)d_in[7];   // [1,128]
    const float* att_dst2 = (const float*)d_in[8];
    const float* b2       = (const float*)d_in[9];   // [128]
    float* out = (float*)d_out;                      // [4096,128]

    // workspace layout
    float* ws   = (float*)d_ws;
    float* as1  = ws;                               // 4096*8 f
    float* ad1  = as1 + 4096 * 8;                   // 4096*8 f
    float* as2  = ad1 + 4096 * 8;                   // 4096 f
    float* ad2  = as2 + 4096;                       // 4096 f
    int*   cnt  = (int*)(ad2 + 4096);               // 4096 i32
    _Float16* x16   = (_Float16*)(cnt + 4096);      // 4096*256
    _Float16* w1T   = x16 + (size_t)4096 * 256;     // 512*256
    _Float16* w2T   = w1T + 512 * 256;              // 128*512
    _Float16* h1g   = w2T + 128 * 512;              // 4096*512
    _Float16* out1h = h1g + (size_t)4096 * 512;     // 4096*512
    _Float16* h2g   = out1h + (size_t)4096 * 512;   // 4096*128
    unsigned short* nbr = (unsigned short*)(h2g + (size_t)4096 * 128); // 4096*STRIDE

    build_nbr_kernel<<<N_NODES, 256, 0, stream>>>(adj, nbr, cnt);
    prep_kernel<<<1792, 256, 0, stream>>>(x, w1, w2, x16, w1T, w2T);

    // layer 1: h1 = x @ w1 (MFMA, fp16 shadow + fused direct scores)
    gemm_mfma_kernel<8, 4, 8><<<512, 256, 0, stream>>>(
        x16, w1T, h1g, att_src1, att_dst1, as1, ad1, 512);
    attn1_kernel<<<N_NODES, 128, 0, stream>>>(h1g, as1, ad1, nbr, cnt, b1, out1h);

    // layer 2: h2 = out1 @ w2 (MFMA)
    gemm_mfma_kernel<16, 8, 1><<<64, 256, 0, stream>>>(
        out1h, w2T, h2g, att_src2, att_dst2, as2, ad2, 128);
    attn2_kernel<<<N_NODES / 2, 128, 0, stream>>>(h2g, as2, ad2, nbr, cnt, b2, out);
}

// Round 9
// 194.533 us; speedup vs baseline: 1.3401x; 1.1155x over previous
//
#include <hip/hip_runtime.h>
#include <hip/hip_bf16.h>
#include <cstdint>

#define N_NODES 4096
#define STRIDE  384      // max degree cap (Binom(4096,0.05): mean 205, 12 sigma)
#define NPAIRS_MAX 192
#define QMAX    128      // per-quarter degree cap in build_nbr
#define WROW    400      // s_w16 head-row stride (u16): 800 B, 16B-aligned

typedef _Float16 half2v __attribute__((ext_vector_type(2)));
typedef _Float16 v4h __attribute__((ext_vector_type(4)));
typedef _Float16 v8h __attribute__((ext_vector_type(8)));
typedef float    v4f __attribute__((ext_vector_type(4)));

// ---- fp16 helpers ---------------------------------------------------------
__device__ __forceinline__ float f16lo(unsigned u) {
    half2v h = __builtin_bit_cast(half2v, u); return (float)h.x;
}
__device__ __forceinline__ float f16hi(unsigned u) {
    half2v h = __builtin_bit_cast(half2v, u); return (float)h.y;
}
__device__ __forceinline__ unsigned pk_lo(unsigned a, unsigned b) {
    return __builtin_amdgcn_perm(b, a, 0x05040100u);
}
__device__ __forceinline__ unsigned pk_hi(unsigned a, unsigned b) {
    return __builtin_amdgcn_perm(b, a, 0x07060302u);
}
__device__ __forceinline__ float fdot2f(unsigned v, unsigned w, float acc) {
    return __builtin_amdgcn_fdot2(__builtin_bit_cast(half2v, v),
                                  __builtin_bit_cast(half2v, w), acc, false);
}
__device__ __forceinline__ float lrelu02(float s) { return (s > 0.f) ? s : 0.2f * s; }
__device__ __forceinline__ float lrelu01(float s) { return (s > 0.f) ? s : 0.01f * s; }

// ---------------------------------------------------------------------------
// 1. Fused: neighbor-list compaction (blocks 0..4095) + fp16 prep of x/w1T/w2T
//    (blocks 4096..5791) + zero-init of layer-2 score accumulators (5792..5807).
// ---------------------------------------------------------------------------
__global__ __launch_bounds__(256) void setup_kernel(
    const float* __restrict__ adj, unsigned short* __restrict__ nbr,
    int* __restrict__ cnt,
    const float* __restrict__ x, const float* __restrict__ w1,
    const float* __restrict__ w2, _Float16* __restrict__ x16,
    _Float16* __restrict__ w1T, _Float16* __restrict__ w2T,
    float* __restrict__ as2, float* __restrict__ ad2) {
    const int b = blockIdx.x, t = threadIdx.x;
    if (b < 4096) {
        const int i    = b;
        const int wv   = t >> 6;
        const int lane = t & 63;
        __shared__ unsigned short s_buf[4][QMAX];
        __shared__ int s_cnt[4];
        const float4* row = (const float4*)(adj + (size_t)i * N_NODES);
        int base = 0;
#pragma unroll
        for (int it = 0; it < 4; it++) {
            float4 v = row[wv * 256 + it * 64 + lane];
            float e4[4] = {v.x, v.y, v.z, v.w};
            unsigned long long m4[4];
#pragma unroll
            for (int e = 0; e < 4; e++) m4[e] = __ballot(e4[e] != 0.0f);
#pragma unroll
            for (int e = 0; e < 4; e++) {
                int prefix = __popcll(m4[e] & ((1ull << lane) - 1ull));
                int pos = base + prefix;
                if (e4[e] != 0.0f && pos < QMAX)
                    s_buf[wv][pos] = (unsigned short)(wv * 1024 + (it * 64 + lane) * 4 + e);
                base += __popcll(m4[e]);
            }
        }
        if (lane == 0) s_cnt[wv] = (base < QMAX) ? base : QMAX;
        __syncthreads();
        const int c0 = s_cnt[0], c1 = s_cnt[1], c2 = s_cnt[2], c3 = s_cnt[3];
        const int o1 = c0, o2 = c0 + c1, o3 = o2 + c2;
        int total = o3 + c3;
        if (total > STRIDE) total = STRIDE;
        for (int k = t; k < total; k += 256) {
            int w, loc;
            if      (k < o1) { w = 0; loc = k; }
            else if (k < o2) { w = 1; loc = k - o1; }
            else if (k < o3) { w = 2; loc = k - o2; }
            else             { w = 3; loc = k - o3; }
            nbr[(size_t)i * STRIDE + k] = s_buf[w][loc];
        }
        if (t == 0) cnt[i] = total;
    } else if (b < 5120) {                // x: 4096*256 elems, 4/thread
        const int idx = (b - 4096) * 1024 + t * 4;
        float4 v = *(const float4*)(x + idx);
        v4h h = { (_Float16)v.x, (_Float16)v.y, (_Float16)v.z, (_Float16)v.w };
        *(v4h*)(x16 + idx) = h;
    } else if (b < 5632) {                // w1T[512][256] <- w1[256][512]
        const int idx = (b - 5120) * 256 + t;
        const int n = idx >> 8, k = idx & 255;
        w1T[idx] = (_Float16)w1[k * 512 + n];
    } else if (b < 5792) {                // w2T[128][512] <- w2[512][128]
        const int idx = (b - 5632) * 410;     // 65536 elems / 160 blocks
        const int e   = idx + t;
        for (int q = e; q < idx + 410 && q < 65536; q += 256) {
            const int n = q >> 9, k = q & 511;
            w2T[q] = (_Float16)w2[k * 128 + n];
        }
    } else {                              // zero as2/ad2 (4096 each, 16 blocks)
        const int idx = (b - 5792) * 256 + t;
        as2[idx] = 0.f;
        ad2[idx] = 0.f;
    }
}

// ---------------------------------------------------------------------------
// 2. MFMA GEMM: C[M,N] = A[M,K] @ B[K,N], fp16 in / fp32 accum. One wave does
//    a 16 x (16*NSUB) strip over full K. Verified layouts: A[m=lane&15][k=
//    quad*8+j]; B[k=quad*8+j][n=lane&15] (from BT16[n][k], contiguous 16B);
//    D[row=quad*4+r][col=lane&15]. Epilogue: fp16 C + fused score partials
//    (H=8: direct store, one wave per row-head; H=1: atomicAdd).
// ---------------------------------------------------------------------------
template<int KCH, int NSUB, int H>
__global__ __launch_bounds__(256) void gemm_mfma_kernel(
    const _Float16* __restrict__ A16, const _Float16* __restrict__ BT16,
    _Float16* __restrict__ C16,
    const float* __restrict__ att_s, const float* __restrict__ att_d,
    float* __restrict__ as_, float* __restrict__ ad_, int N) {
    const int K    = KCH * 32;
    const int wid  = blockIdx.x * 4 + (threadIdx.x >> 6);
    const int lane = threadIdx.x & 63;
    const int quad = lane >> 4, l16 = lane & 15;
    const int ntiles = N / (16 * NSUB);
    const int m0 = (wid / ntiles) * 16;
    const int n0 = (wid % ntiles) * (16 * NSUB);

    v8h a[KCH];
    const v8h* arow = (const v8h*)(A16 + (size_t)(m0 + l16) * K + quad * 8);
#pragma unroll
    for (int c = 0; c < KCH; c++) a[c] = arow[c * 4];

    float ps[4] = {}, pd[4] = {};
#pragma unroll
    for (int s = 0; s < NSUB; s++) {
        const int n = n0 + s * 16 + l16;
        const v8h* brow = (const v8h*)(BT16 + (size_t)n * K + quad * 8);
        v4f acc = {0.f, 0.f, 0.f, 0.f};
#pragma unroll
        for (int c = 0; c < KCH; c++)
            acc = __builtin_amdgcn_mfma_f32_16x16x32_f16(a[c], brow[c * 4], acc, 0, 0, 0);
        const float sa = att_s[n], sd = att_d[n];
#pragma unroll
        for (int r = 0; r < 4; r++) {
            C16[(size_t)(m0 + quad * 4 + r) * N + n] = (_Float16)acc[r];
            ps[r] += acc[r] * sa;
            pd[r] += acc[r] * sd;
        }
    }
#pragma unroll
    for (int r = 0; r < 4; r++) {
#pragma unroll
        for (int off = 1; off < 16; off <<= 1) {
            ps[r] += __shfl_xor(ps[r], off);
            pd[r] += __shfl_xor(pd[r], off);
        }
    }
    if (l16 == 0) {
#pragma unroll
        for (int r = 0; r < 4; r++) {
            const int row = m0 + quad * 4 + r;
            if (H > 1) {
                const int head = n0 >> 6;
                as_[row * H + head] = ps[r];
                ad_[row * H + head] = pd[r];
            } else {
                atomicAdd(&as_[row], ps[r]);
                atomicAdd(&ad_[row], pd[r]);
            }
        }
    }
}

// ---------------------------------------------------------------------------
// 3. Layer-1 sparse aggregate, flash-split: one block (2 waves) per row.
//    Wave wv owns alternating 64-edge chunks — computes its OWN partial max,
//    fp16 weights (no duplicate LDS writes), denominator and output. One
//    barrier; wave1 merges with exact fp32 rescale and writes fp16 out1.
// ---------------------------------------------------------------------------
__global__ __launch_bounds__(128) void attn1_kernel(
    const _Float16* __restrict__ h1g, const float* __restrict__ asrc,
    const float* __restrict__ adst, const unsigned short* __restrict__ nbr,
    const int* __restrict__ cnt, const float* __restrict__ b1,
    _Float16* __restrict__ out1f16) {
    const int i    = blockIdx.x;
    const int wv   = threadIdx.x >> 6;
    const int lane = threadIdx.x & 63;
    const int hd   = lane >> 3;               // head of this lane (8 ch each)
    __shared__ __align__(16) unsigned s_nb[NPAIRS_MAX];
    __shared__ __align__(16) unsigned short s_w16[8][WROW];
    __shared__ __align__(16) float s_comb[512];
    __shared__ float s_ml[2][2][8];

    const int n      = cnt[i];
    const int npairs = (n + 1) >> 1;
    const int nq     = (npairs + 3) >> 2;     // pair-quads (8 edges each)
    const int npadp  = nq * 4;
    const int npadE  = npadp * 2;

    // stage OWNED pair chunks (32 pairs per 64-edge chunk, interleaved by wv)
    const unsigned* nbr32 = (const unsigned*)(nbr + (size_t)i * STRIDE);
    for (int k0 = wv * 32; k0 < npadp; k0 += 128) {
        const int k = k0 + (lane & 31) + ((lane >= 32) ? 64 : 0);
        if (k < npadp) {
            unsigned v = 0u;
            if (2 * k + 1 < n)  v = nbr32[k];
            else if (2 * k < n) v = nbr32[k] & 0xffffu;
            s_nb[k] = v;
        }
    }

    float ad8[8];
    {
        const float4 a0 = *(const float4*)(adst + i * 8);
        const float4 a1 = *(const float4*)(adst + i * 8 + 4);
        ad8[0]=a0.x; ad8[1]=a0.y; ad8[2]=a0.z; ad8[3]=a0.w;
        ad8[4]=a1.x; ad8[5]=a1.y; ad8[6]=a1.z; ad8[7]=a1.w;
    }
    // phase A: per-head max over OWNED edges
    float m8[8];
#pragma unroll
    for (int k = 0; k < 8; k++) m8[k] = -1e30f;
    for (int e0 = wv * 64; e0 < n; e0 += 128) {
        const int e = e0 + lane;
        if (e < n) {
            const int id = (s_nb[e >> 1] >> ((e & 1) * 16)) & 0xffff;
            const float4 q0 = *(const float4*)(asrc + id * 8);
            const float4 q1 = *(const float4*)(asrc + id * 8 + 4);
            const float sv[8] = {q0.x, q0.y, q0.z, q0.w, q1.x, q1.y, q1.z, q1.w};
#pragma unroll
            for (int k = 0; k < 8; k++) m8[k] = fmaxf(m8[k], lrelu02(sv[k] + ad8[k]));
        }
    }
#pragma unroll
    for (int k = 0; k < 8; k++)
#pragma unroll
        for (int off = 32; off; off >>= 1) m8[k] = fmaxf(m8[k], __shfl_xor(m8[k], off));

    // phase B: exp vs OWN max, fp16 weights -> LDS (owned edges + pads only),
    // denominator from the rounded fp16 weights.
    float l8[8];
#pragma unroll
    for (int k = 0; k < 8; k++) l8[k] = 0.f;
    for (int e0 = wv * 64; e0 < npadE; e0 += 128) {
        const int e = e0 + lane;
        if (e < npadE) {
            if (e < n) {
                const int id = (s_nb[e >> 1] >> ((e & 1) * 16)) & 0xffff;
                const float4 q0 = *(const float4*)(asrc + id * 8);
                const float4 q1 = *(const float4*)(asrc + id * 8 + 4);
                const float sv[8] = {q0.x, q0.y, q0.z, q0.w, q1.x, q1.y, q1.z, q1.w};
#pragma unroll
                for (int k = 0; k < 8; k++) {
                    float ev = __expf(lrelu02(sv[k] + ad8[k]) - m8[k]);
                    _Float16 h = (_Float16)ev;
                    l8[k] += (float)h;
                    s_w16[k][e] = __builtin_bit_cast(unsigned short, h);
                }
            } else {
#pragma unroll
                for (int k = 0; k < 8; k++) s_w16[k][e] = 0;
            }
        }
    }
#pragma unroll
    for (int k = 0; k < 8; k++)
#pragma unroll
        for (int off = 32; off; off >>= 1) l8[k] += __shfl_xor(l8[k], off);

    // pass 3: gather OWNED quads (8 per chunk, interleaved by wv).
    const char* hb = (const char*)h1g + lane * 16;
    float ac[8] = {};
    for (int q0 = wv * 8; q0 < nq; q0 += 16) {
#pragma unroll
        for (int qq = 0; qq < 8; qq++) {
            const int q = q0 + qq;
            if (q >= nq) break;
            const uint4 idq = *(const uint4*)&s_nb[q * 4];
            const uint4 wq  = *(const uint4*)((const unsigned*)&s_w16[hd][0] + q * 4);
            const unsigned idv[4] = {idq.x, idq.y, idq.z, idq.w};
            const unsigned wv4[4] = {wq.x, wq.y, wq.z, wq.w};
#pragma unroll
            for (int p = 0; p < 4; p++) {
                const int iA = idv[p] & 0xffff, iB = idv[p] >> 16;
                const uint4 vA = *(const uint4*)(hb + (size_t)iA * 1024);
                const uint4 vB = *(const uint4*)(hb + (size_t)iB * 1024);
                const unsigned w = wv4[p];
                ac[0] = fdot2f(pk_lo(vA.x, vB.x), w, ac[0]);
                ac[1] = fdot2f(pk_hi(vA.x, vB.x), w, ac[1]);
                ac[2] = fdot2f(pk_lo(vA.y, vB.y), w, ac[2]);
                ac[3] = fdot2f(pk_hi(vA.y, vB.y), w, ac[3]);
                ac[4] = fdot2f(pk_lo(vA.z, vB.z), w, ac[4]);
                ac[5] = fdot2f(pk_hi(vA.z, vB.z), w, ac[5]);
                ac[6] = fdot2f(pk_lo(vA.w, vB.w), w, ac[6]);
                ac[7] = fdot2f(pk_hi(vA.w, vB.w), w, ac[7]);
            }
        }
    }
    // exchange: wave0's partial output + both waves' (m, l) per head
    if (wv == 0) {
        *(float4*)&s_comb[lane * 8]     = make_float4(ac[0], ac[1], ac[2], ac[3]);
        *(float4*)&s_comb[lane * 8 + 4] = make_float4(ac[4], ac[5], ac[6], ac[7]);
    }
    if (lane == 0) {
#pragma unroll
        for (int k = 0; k < 8; k++) {
            s_ml[wv][0][k] = m8[k];
            s_ml[wv][1][k] = l8[k];
        }
    }
    __syncthreads();
    if (wv == 1) {
        const float m0v = s_ml[0][0][hd], l0v = s_ml[0][1][hd];
        const float m1v = s_ml[1][0][hd], l1v = s_ml[1][1][hd];
        const float mm = fmaxf(m0v, m1v);
        const float a0s = __expf(m0v - mm), a1s = __expf(m1v - mm);
        const float den = l0v * a0s + l1v * a1s;
        const float inv = 1.0f / den;
        const float4 c0 = *(const float4*)&s_comb[lane * 8];
        const float4 c1 = *(const float4*)&s_comb[lane * 8 + 4];
        const float o8[8] = {
            c0.x * a0s + ac[0] * a1s, c0.y * a0s + ac[1] * a1s,
            c0.z * a0s + ac[2] * a1s, c0.w * a0s + ac[3] * a1s,
            c1.x * a0s + ac[4] * a1s, c1.y * a0s + ac[5] * a1s,
            c1.z * a0s + ac[6] * a1s, c1.w * a0s + ac[7] * a1s };
        const float4 bb0 = *(const float4*)(b1 + lane * 8);
        const float4 bb1 = *(const float4*)(b1 + lane * 8 + 4);
        const float bbv[8] = {bb0.x, bb0.y, bb0.z, bb0.w, bb1.x, bb1.y, bb1.z, bb1.w};
        v8h ov;
#pragma unroll
        for (int c = 0; c < 8; c++)
            ov[c] = (_Float16)lrelu01(o8[c] * inv + bbv[c]);
        *(v8h*)(out1f16 + (size_t)i * 512 + lane * 8) = ov;
    }
}

// ---------------------------------------------------------------------------
// 4. Layer-2 sparse aggregate: one wave per row, 4 edges per gather inst.
// ---------------------------------------------------------------------------
__global__ __launch_bounds__(128) void attn2_kernel(
    const _Float16* __restrict__ h2g, const float* __restrict__ asrc,
    const float* __restrict__ adst, const unsigned short* __restrict__ nbr,
    const int* __restrict__ cnt, const float* __restrict__ b2,
    float* __restrict__ out) {
    const int wv   = threadIdx.x >> 6;
    const int i    = blockIdx.x * 2 + wv;
    const int lane = threadIdx.x & 63;
    const int grp  = lane >> 4, l16 = lane & 15;
    __shared__ __align__(16) unsigned s_nb[2][NPAIRS_MAX];
    __shared__ __align__(16) unsigned short s_w16[2][STRIDE + 16];

    const int n     = cnt[i];
    const int nq4   = (n + 3) >> 2;
    const int npad4 = nq4 * 4;
    const int npadp = (npad4 + 1) >> 1;

    const unsigned* nbr32 = (const unsigned*)(nbr + (size_t)i * STRIDE);
    for (int k = lane; k < npadp; k += 64) {
        unsigned v = 0u;
        if (2 * k + 1 < n)  v = nbr32[k];
        else if (2 * k < n) v = nbr32[k] & 0xffffu;
        s_nb[wv][k] = v;
    }

    const float ad = adst[i];
    float sreg[6];
    float m = -1e30f;
#pragma unroll
    for (int it = 0; it < 6; it++) {
        const int e = it * 64 + lane;
        float s = -1e30f;
        if (e < n) {
            const int id = (s_nb[wv][e >> 1] >> ((e & 1) * 16)) & 0xffff;
            s = lrelu02(asrc[id] + ad);
        }
        sreg[it] = s;
        m = fmaxf(m, s);
    }
#pragma unroll
    for (int off = 32; off; off >>= 1) m = fmaxf(m, __shfl_xor(m, off));
    float l = 0.f;
#pragma unroll
    for (int it = 0; it < 6; it++) {
        const int e = it * 64 + lane;
        if (e < n) {
            float ev = __expf(sreg[it] - m);
            _Float16 h = (_Float16)ev;
            l += (float)h;
            s_w16[wv][e] = __builtin_bit_cast(unsigned short, h);
        }
    }
    if (lane < npad4 - n) s_w16[wv][n + lane] = 0;
#pragma unroll
    for (int off = 32; off; off >>= 1) l += __shfl_xor(l, off);
    const float inv = 1.0f / l;

    const char* hb = (const char*)h2g + l16 * 16;
    float ac[8] = {};
    for (int it = 0; it < nq4; it++) {
        const int e = it * 4 + grp;
        const unsigned pr = s_nb[wv][e >> 1];
        const int id = (e & 1) ? (int)(pr >> 16) : (int)(pr & 0xffffu);
        const float w = (float)((const _Float16*)&s_w16[wv][0])[e];
        const uint4 v = *(const uint4*)(hb + (size_t)id * 256);
        ac[0] += w * f16lo(v.x); ac[1] += w * f16hi(v.x);
        ac[2] += w * f16lo(v.y); ac[3] += w * f16hi(v.y);
        ac[4] += w * f16lo(v.z); ac[5] += w * f16hi(v.z);
        ac[6] += w * f16lo(v.w); ac[7] += w * f16hi(v.w);
    }
#pragma unroll
    for (int c = 0; c < 8; c++) {
        ac[c] += __shfl_xor(ac[c], 16);
        ac[c] += __shfl_xor(ac[c], 32);
    }
    if (lane < 16) {
        const float4 bb0 = *(const float4*)(b2 + lane * 8);
        const float4 bb1 = *(const float4*)(b2 + lane * 8 + 4);
        float4 o0, o1;
        o0.x = lrelu01(ac[0] * inv + bb0.x);
        o0.y = lrelu01(ac[1] * inv + bb0.y);
        o0.z = lrelu01(ac[2] * inv + bb0.z);
        o0.w = lrelu01(ac[3] * inv + bb0.w);
        o1.x = lrelu01(ac[4] * inv + bb1.x);
        o1.y = lrelu01(ac[5] * inv + bb1.y);
        o1.z = lrelu01(ac[6] * inv + bb1.z);
        o1.w = lrelu01(ac[7] * inv + bb1.w);
        *(float4*)(out + (size_t)i * 128 + lane * 8)     = o0;
        *(float4*)(out + (size_t)i * 128 + lane * 8 + 4) = o1;
    }
}

// ---------------------------------------------------------------------------
extern "C" void kernel_launch(void* const* d_in, const int* in_sizes, int n_in,
                              void* d_out, int out_size, void* d_ws, size_t ws_size,
                              hipStream_t stream) {
    const float* x        = (const float*)d_in[0];   // [4096,256]
    const float* adj      = (const float*)d_in[1];   // [4096,4096]
    const float* w1       = (const float*)d_in[2];   // [256,512]
    const float* att_src1 = (const float*)d_in[3];   // [8,64]
    const float* att_dst1 = (const float*)d_in[4];
    const float* b1       = (const float*)d_in[5];   // [512]
    const float* w2       = (const float*)d_in[6];   // [512,128]
    const float* att_src2 = (const float*)d_in[7];   // [1,128]
    const float* att_dst2 = (const float*)d_in[8];
    const float* b2       = (const float*)d_in[9];   // [128]
    float* out = (float*)d_out;                      // [4096,128]

    float* ws   = (float*)d_ws;
    float* as1  = ws;                               // 4096*8 f
    float* ad1  = as1 + 4096 * 8;                   // 4096*8 f
    float* as2  = ad1 + 4096 * 8;                   // 4096 f
    float* ad2  = as2 + 4096;                       // 4096 f
    int*   cnt  = (int*)(ad2 + 4096);               // 4096 i32
    _Float16* x16   = (_Float16*)(cnt + 4096);      // 4096*256
    _Float16* w1T   = x16 + (size_t)4096 * 256;     // 512*256
    _Float16* w2T   = w1T + 512 * 256;              // 128*512
    _Float16* h1g   = w2T + 128 * 512;              // 4096*512
    _Float16* out1h = h1g + (size_t)4096 * 512;     // 4096*512
    _Float16* h2g   = out1h + (size_t)4096 * 512;   // 4096*128
    unsigned short* nbr = (unsigned short*)(h2g + (size_t)4096 * 128); // 4096*STRIDE

    setup_kernel<<<5808, 256, 0, stream>>>(adj, nbr, cnt, x, w1, w2,
                                           x16, w1T, w2T, as2, ad2);

    // layer 1: h1 = x @ w1 (MFMA, fp16 shadow + fused direct scores)
    gemm_mfma_kernel<8, 4, 8><<<512, 256, 0, stream>>>(
        x16, w1T, h1g, att_src1, att_dst1, as1, ad1, 512);
    attn1_kernel<<<N_NODES, 128, 0, stream>>>(h1g, as1, ad1, nbr, cnt, b1, out1h);

    // layer 2: h2 = out1 @ w2 (MFMA, 256 blocks, atomic score partials)
    gemm_mfma_kernel<16, 2, 1><<<256, 256, 0, stream>>>(
        out1h, w2T, h2g, att_src2, att_dst2, as2, ad2, 128);
    attn2_kernel<<<N_NODES / 2, 128, 0, stream>>>(h2g, as2, ad2, nbr, cnt, b2, out);
}